// Round 13
// baseline (583.948 us; speedup 1.0000x reference)
//
#include <hip/hip_runtime.h>

// L2RegressionAttention — chunked WY-transform.
// r13: GEMM tile widened to 128x256 (4 waves x 64x128 out, acc 4x8) — 32 MFMA
// per wave per K-step against the same per-step drain+barrier, 2x arithmetic
// intensity on A. Same 2-buf drain staging, plain block order (A L2-resident).
// phase1/levels/phase3 byte-identical to r12.
// B=4, S=4096, D=1024, H=16, hd=64, eta = 0.1/4 = 0.025.

typedef unsigned short u16;
typedef __attribute__((ext_vector_type(8))) short short8;
typedef __attribute__((ext_vector_type(4))) float f32x4;

#define B_ 4
#define S_ 4096
#define D_ 1024
#define H_ 16
#define CHUNK 16
#define NCHUNK 256
#define SUPW 16
#define NSUP 16
#define ETA 0.025f

__device__ __forceinline__ u16 f2bf(float f) {
  unsigned u = __builtin_bit_cast(unsigned, f);
  u += 0x7fffu + ((u >> 16) & 1u);
  return (u16)(u >> 16);
}
__device__ __forceinline__ float bf2f(u16 s) {
  unsigned u = ((unsigned)s) << 16;
  return __builtin_bit_cast(float, u);
}
__device__ __forceinline__ float ldv(float v) { return v; }
__device__ __forceinline__ float ldv(u16 v) { return bf2f(v); }
__device__ __forceinline__ void stv(float* p, float v) { *p = v; }
__device__ __forceinline__ void stv(u16* p, float v) { *p = f2bf(v); }

#define MFMA __builtin_amdgcn_mfma_f32_16x16x32_bf16

__device__ __forceinline__ void gload16(const void* g, void* l) {
  __builtin_amdgcn_global_load_lds(
      (__attribute__((address_space(1))) void*)g,
      (__attribute__((address_space(3))) void*)l, 16, 0, 0);
}

// ---------------- fp32 -> bf16 hi-only convert ----------------
__global__ void cvt_hi_kernel(const float* __restrict__ x, u16* __restrict__ hi, int n4) {
  int i = blockIdx.x * blockDim.x + threadIdx.x;
  int stride = gridDim.x * blockDim.x;
  for (; i < n4; i += stride) {
    float4 v = ((const float4*)x)[i];
    ushort4 h;
    h.x = f2bf(v.x); h.y = f2bf(v.y); h.z = f2bf(v.z); h.w = f2bf(v.w);
    ((ushort4*)hi)[i] = h;
  }
}

// ---------------- GEMM: C[M][N] = A * B^T, 128x256 tile ----------------
// 4 waves, each 64x128 output (acc[4][8]). 2-buf drain staging via gload_lds
// (A: 2/wave, B: 4/wave). BPRE=0: B fp32 converted on the fly.
template<int BPRE, typename OutT>
__global__ __launch_bounds__(256) void gemm_axw(
    const u16* __restrict__ Ahg, const void* __restrict__ Bhp,
    OutT* __restrict__ C, int M, int N, int K) {
  __shared__ __align__(16) u16 Ahs[2][128][32];
  __shared__ __align__(16) u16 Bhs[2][256][32];
  const int tid = threadIdx.x, w = tid >> 6, lane = tid & 63;
  const int bm = blockIdx.x * 128, bn = blockIdx.y * 256;
  const int wm = (w >> 1) * 64, wn = (w & 1) * 128;
  const int fr = lane & 15, kb = lane >> 4;
  const int lrow = lane >> 2, lcol = (lane & 3) * 8;

  auto stage = [&](int buf, int k0) {
    {
      const size_t rb = (size_t)(bm + w * 32 + lrow) * K + k0 + lcol;
      gload16(Ahg + rb, &Ahs[buf][w * 32][0]);
      gload16(Ahg + rb + (size_t)16 * K, &Ahs[buf][w * 32 + 16][0]);
    }
    if constexpr (BPRE) {
      const u16* Bhg = (const u16*)Bhp;
      const size_t rb = (size_t)(bn + w * 64 + lrow) * K + k0 + lcol;
      gload16(Bhg + rb, &Bhs[buf][w * 64][0]);
      gload16(Bhg + rb + (size_t)16 * K, &Bhs[buf][w * 64 + 16][0]);
      gload16(Bhg + rb + (size_t)32 * K, &Bhs[buf][w * 64 + 32][0]);
      gload16(Bhg + rb + (size_t)48 * K, &Bhs[buf][w * 64 + 48][0]);
    } else {
      const float* Bm = (const float*)Bhp;
#pragma unroll
      for (int i2 = 0; i2 < 8; ++i2) {
        int e = tid + i2 * 256, r = e >> 3, sg = (e & 7) * 4;
        float4 v = *(const float4*)(&Bm[(size_t)(bn + r) * K + k0 + sg]);
        ushort4 hq;
        hq.x = f2bf(v.x); hq.y = f2bf(v.y); hq.z = f2bf(v.z); hq.w = f2bf(v.w);
        *(ushort4*)(&Bhs[buf][r][sg]) = hq;
      }
    }
  };
  auto compute = [&](int buf, f32x4 (*acc)[8]) {
    short8 ah[4], bh[8];
#pragma unroll
    for (int mi = 0; mi < 4; ++mi)
      ah[mi] = *(const short8*)(&Ahs[buf][wm + mi * 16 + fr][kb * 8]);
#pragma unroll
    for (int ni = 0; ni < 8; ++ni)
      bh[ni] = *(const short8*)(&Bhs[buf][wn + ni * 16 + fr][kb * 8]);
#pragma unroll
    for (int mi = 0; mi < 4; ++mi)
#pragma unroll
      for (int ni = 0; ni < 8; ++ni)
        acc[mi][ni] = MFMA(ah[mi], bh[ni], acc[mi][ni], 0, 0, 0);
  };

  f32x4 acc[4][8];
#pragma unroll
  for (int i = 0; i < 4; ++i)
#pragma unroll
    for (int j = 0; j < 8; ++j) acc[i][j] = (f32x4){0.f, 0.f, 0.f, 0.f};

  const int nt = K >> 5;
  stage(0, 0);
  asm volatile("s_waitcnt vmcnt(0)" ::: "memory");
  __syncthreads();
  int cur = 0;
  for (int t = 0; t < nt; ++t) {
    if (t + 1 < nt) stage(cur ^ 1, (t + 1) * 32);  // issue-early into other buf
    compute(cur, acc);
    asm volatile("s_waitcnt vmcnt(0)" ::: "memory");
    __syncthreads();
    cur ^= 1;
  }
  const int fc = lane & 15, fr4 = (lane >> 4) * 4;
#pragma unroll
  for (int mi = 0; mi < 4; ++mi)
#pragma unroll
    for (int ni = 0; ni < 8; ++ni) {
      int gm = bm + wm + mi * 16 + fr4;
      int gn = bn + wn + ni * 16 + fc;
#pragma unroll
      for (int rg = 0; rg < 4; ++rg)
        stv(&C[(size_t)(gm + rg) * N + gn], acc[mi][ni][rg]);
    }
}

// ---------------- phase 1 (MFMA, pre-masked N, fused U/W) — r12 ----------------
template<typename PT>
__global__ __launch_bounds__(256) void phase1_kernel(
    float* __restrict__ Qg, const u16* __restrict__ Kg, u16* __restrict__ Vg,
    PT* __restrict__ Pg, PT* __restrict__ Rg) {
  __shared__ __align__(16) u16 Ks[64][72];
  __shared__ __align__(16) u16 KsT[64][72];
  __shared__ __align__(16) u16 Gh[64][72];
  __shared__ __align__(16) u16 Gl[64][72];
  __shared__ __align__(16) u16 Xs[64][72];
  __shared__ __align__(16) float Ut[64][68];
  __shared__ __align__(16) float Wt[64][68];

  const int c = blockIdx.x, h = blockIdx.y, tid = threadIdx.x;
  const int w = tid >> 6, lane = tid & 63;
  const int fr = lane & 15, kq = lane >> 4, orow = kq * 4;
  const int xr = 16 * w + fr;

  auto gidx = [&](int r, int d) -> size_t {
    return ((size_t)(r & 3) * S_ + (size_t)c * CHUNK + (r >> 2)) * D_ + h * 64 + d;
  };
  auto ldb = [&](const u16 (*M)[72], int row, int s) -> short8 {
    return *(const short8*)(&M[row][32 * s + 8 * kq]);
  };
  auto ldf = [&](const float (*M)[68], int row, int s, short8& hh, short8& ll) {
    const float* p = &M[row][32 * s + 8 * kq];
#pragma unroll
    for (int j = 0; j < 8; ++j) {
      float v = p[j];
      u16 hb = f2bf(v);
      hh[j] = (short)hb;
      ll[j] = (short)f2bf(v - bf2f(hb));
    }
  };
  auto ldfh = [&](const float (*M)[68], int row, int s) -> short8 {
    const float* p = &M[row][32 * s + 8 * kq];
    short8 hh;
#pragma unroll
    for (int j = 0; j < 8; ++j) hh[j] = (short)f2bf(p[j]);
    return hh;
  };

  for (int i = tid; i < 4096; i += 256) {
    int r = i >> 6, d = i & 63;
    size_t g = gidx(r, d);
    u16 kraw = Kg[g];
    Ks[r][d] = kraw;
    KsT[d][r] = kraw;
    Wt[d][r] = ETA * bf2f(kraw);
    Ut[d][r] = ETA * bf2f(Vg[g]);
  }
  __syncthreads();  // (1)

  f32x4 gacc[4];
#pragma unroll
  for (int ni = 0; ni < 4; ++ni) gacc[ni] = (f32x4){0.f, 0.f, 0.f, 0.f};
  {
    short8 xf[2];
#pragma unroll
    for (int s = 0; s < 2; ++s) xf[s] = ldb(Ks, xr, s);
#pragma unroll
    for (int ni = 0; ni < 4; ++ni)
#pragma unroll
      for (int s = 0; s < 2; ++s)
        gacc[ni] = MFMA(xf[s], ldb(Ks, 16 * ni + fr, s), gacc[ni], 0, 0, 0);
  }

  float sreg[4][4];
  {
    short8 xh[2], xl[2];
#pragma unroll
    for (int s = 0; s < 2; ++s) {
      const float* qp = &Qg[gidx(xr, 32 * s + 8 * kq)];
#pragma unroll
      for (int j = 0; j < 8; ++j) {
        float v = qp[j];
        u16 hb = f2bf(v);
        xh[s][j] = (short)hb;
        xl[s][j] = (short)f2bf(v - bf2f(hb));
      }
    }
    f32x4 acc[4];
#pragma unroll
    for (int ni = 0; ni < 4; ++ni) acc[ni] = (f32x4){0.f, 0.f, 0.f, 0.f};
#pragma unroll
    for (int ni = 0; ni < 4; ++ni)
#pragma unroll
      for (int s = 0; s < 2; ++s) {
        short8 yf = ldb(Ks, 16 * ni + fr, s);
        acc[ni] = MFMA(xh[s], yf, acc[ni], 0, 0, 0);
        acc[ni] = MFMA(xl[s], yf, acc[ni], 0, 0, 0);
      }
#pragma unroll
    for (int ni = 0; ni < 4; ++ni)
#pragma unroll
      for (int rg = 0; rg < 4; ++rg) {
        int r = 16 * w + orow + rg, cc = 16 * ni + fr;
        sreg[ni][rg] = ((r >> 2) >= (cc >> 2)) ? acc[ni][rg] : 0.f;
      }
  }
  __syncthreads();  // (1b)

#pragma unroll
  for (int ni = 0; ni < 4; ++ni)
#pragma unroll
    for (int rg = 0; rg < 4; ++rg) {
      float v = -ETA * gacc[ni][rg];
      u16 hb = f2bf(v);
      u16 lb = f2bf(v - bf2f(hb));
      int rr = 16 * w + orow + rg, cc = 16 * ni + fr;
      bool low = (rr >> 2) > (cc >> 2);
      u16 hm = low ? hb : (u16)0, lm = low ? lb : (u16)0;
      Gh[rr][cc] = hm;
      Gl[rr][cc] = lm;
      Ks[cc][rr] = hm;
      Xs[cc][rr] = lm;
    }
  __syncthreads();  // (2)

  {
    short8 uh[2], ul[2], wh[2], wl[2];
#pragma unroll
    for (int s = 0; s < 2; ++s) { ldf(Ut, xr, s, uh[s], ul[s]); ldf(Wt, xr, s, wh[s], wl[s]); }
    f32x4 aU[4], aW[4];
#pragma unroll
    for (int ni = 0; ni < 4; ++ni) { aU[ni] = (f32x4){0.f,0.f,0.f,0.f}; aW[ni] = (f32x4){0.f,0.f,0.f,0.f}; }
#pragma unroll
    for (int ni = 0; ni < 4; ++ni)
#pragma unroll
      for (int s = 0; s < 2; ++s) {
        short8 yh = ldb(Gh, 16 * ni + fr, s);
        short8 yl = ldb(Gl, 16 * ni + fr, s);
        aU[ni] = MFMA(uh[s], yh, aU[ni], 0, 0, 0);
        aU[ni] = MFMA(uh[s], yl, aU[ni], 0, 0, 0);
        aU[ni] = MFMA(ul[s], yh, aU[ni], 0, 0, 0);
        aW[ni] = MFMA(wh[s], yh, aW[ni], 0, 0, 0);
        aW[ni] = MFMA(wh[s], yl, aW[ni], 0, 0, 0);
        aW[ni] = MFMA(wl[s], yh, aW[ni], 0, 0, 0);
      }
#pragma unroll
    for (int ni = 0; ni < 4; ++ni)
#pragma unroll
      for (int rg = 0; rg < 4; ++rg) {
        Ut[16 * w + orow + rg][16 * ni + fr] += aU[ni][rg];
        Wt[16 * w + orow + rg][16 * ni + fr] += aW[ni][rg];
      }
  }
  auto appSf = [&](const u16 (*Np)[72]) {
    short8 xu[2], xw[2];
#pragma unroll
    for (int s = 0; s < 2; ++s) { xu[s] = ldfh(Ut, xr, s); xw[s] = ldfh(Wt, xr, s); }
    f32x4 aU[4], aW[4];
#pragma unroll
    for (int ni = 0; ni < 4; ++ni) { aU[ni] = (f32x4){0.f,0.f,0.f,0.f}; aW[ni] = (f32x4){0.f,0.f,0.f,0.f}; }
#pragma unroll
    for (int ni = 0; ni < 4; ++ni)
#pragma unroll
      for (int s = 0; s < 2; ++s) {
        short8 yf = ldb(Np, 16 * ni + fr, s);
        aU[ni] = MFMA(xu[s], yf, aU[ni], 0, 0, 0);
        aW[ni] = MFMA(xw[s], yf, aW[ni], 0, 0, 0);
      }
#pragma unroll
    for (int ni = 0; ni < 4; ++ni)
#pragma unroll
      for (int rg = 0; rg < 4; ++rg) {
        Ut[16 * w + orow + rg][16 * ni + fr] += aU[ni][rg];
        Wt[16 * w + orow + rg][16 * ni + fr] += aW[ni][rg];
      }
  };

  {
    f32x4 sq[4];
#pragma unroll
    for (int ni = 0; ni < 4; ++ni) sq[ni] = (f32x4){0.f, 0.f, 0.f, 0.f};
    short8 xh[2], xl[2];
#pragma unroll
    for (int s = 0; s < 2; ++s) { xh[s] = ldb(Gh, xr, s); xl[s] = ldb(Gl, xr, s); }
#pragma unroll
    for (int ni = 0; ni < 4; ++ni)
#pragma unroll
      for (int s = 0; s < 2; ++s) {
        short8 yh = ldb(Ks, 16 * ni + fr, s);
        short8 yl = ldb(Xs, 16 * ni + fr, s);
        sq[ni] = MFMA(xh[s], yh, sq[ni], 0, 0, 0);
        sq[ni] = MFMA(xh[s], yl, sq[ni], 0, 0, 0);
        sq[ni] = MFMA(xl[s], yh, sq[ni], 0, 0, 0);
      }
    __syncthreads();  // (3)
#pragma unroll
    for (int ni = 0; ni < 4; ++ni)
#pragma unroll
      for (int rg = 0; rg < 4; ++rg) {
        u16 b = f2bf(sq[ni][rg]);
        int rr = 16 * w + orow + rg, cc = 16 * ni + fr;
        Ks[rr][cc] = b;
        Gh[cc][rr] = b;
      }
  }
  __syncthreads();  // (4)

  appSf(Ks);
  {
    f32x4 sq[4];
#pragma unroll
    for (int ni = 0; ni < 4; ++ni) sq[ni] = (f32x4){0.f, 0.f, 0.f, 0.f};
    short8 xf[2];
#pragma unroll
    for (int s = 0; s < 2; ++s) xf[s] = ldb(Ks, xr, s);
#pragma unroll
    for (int ni = 0; ni < 4; ++ni)
#pragma unroll
      for (int s = 0; s < 2; ++s)
        sq[ni] = MFMA(xf[s], ldb(Gh, 16 * ni + fr, s), sq[ni], 0, 0, 0);
    __syncthreads();  // (5)
#pragma unroll
    for (int ni = 0; ni < 4; ++ni)
#pragma unroll
      for (int rg = 0; rg < 4; ++rg) {
        u16 b = f2bf(sq[ni][rg]);
        int rr = 16 * w + orow + rg, cc = 16 * ni + fr;
        Gl[rr][cc] = b;
        Ks[cc][rr] = b;
      }
  }
  __syncthreads();  // (6)

  appSf(Gl);
  {
    f32x4 sq[4];
#pragma unroll
    for (int ni = 0; ni < 4; ++ni) sq[ni] = (f32x4){0.f, 0.f, 0.f, 0.f};
    short8 xf[2];
#pragma unroll
    for (int s = 0; s < 2; ++s) xf[s] = ldb(Gl, xr, s);
#pragma unroll
    for (int ni = 0; ni < 4; ++ni)
#pragma unroll
      for (int s = 0; s < 2; ++s)
        sq[ni] = MFMA(xf[s], ldb(Ks, 16 * ni + fr, s), sq[ni], 0, 0, 0);
#pragma unroll
    for (int ni = 0; ni < 4; ++ni)
#pragma unroll
      for (int rg = 0; rg < 4; ++rg)
        Gh[16 * w + orow + rg][16 * ni + fr] = f2bf(sq[ni][rg]);
  }
  __syncthreads();  // (7)

  appSf(Gh);
  __syncthreads();  // (7b)

  const size_t base = ((size_t)c * H_ + h) * 4096;
  {
    short8 wh[2], wl[2], uh[2], ul[2];
#pragma unroll
    for (int s = 0; s < 2; ++s) { ldf(Wt, xr, s, wh[s], wl[s]); ldf(Ut, xr, s, uh[s], ul[s]); }
    f32x4 aP[4], aR[4];
#pragma unroll
    for (int ni = 0; ni < 4; ++ni) { aP[ni] = (f32x4){0.f,0.f,0.f,0.f}; aR[ni] = (f32x4){0.f,0.f,0.f,0.f}; }
#pragma unroll
    for (int ni = 0; ni < 4; ++ni)
#pragma unroll
      for (int s = 0; s < 2; ++s) {
        short8 yf = ldb(KsT, 16 * ni + fr, s);
        aP[ni] = MFMA(wh[s], yf, aP[ni], 0, 0, 0);
        aP[ni] = MFMA(wl[s], yf, aP[ni], 0, 0, 0);
        aR[ni] = MFMA(uh[s], yf, aR[ni], 0, 0, 0);
        aR[ni] = MFMA(ul[s], yf, aR[ni], 0, 0, 0);
      }
#pragma unroll
    for (int ni = 0; ni < 4; ++ni)
#pragma unroll
      for (int rg = 0; rg < 4; ++rg) {
        stv(&Pg[base + (16 * w + orow + rg) * 64 + 16 * ni + fr], aP[ni][rg]);
        stv(&Rg[base + (16 * w + orow + rg) * 64 + 16 * ni + fr], aR[ni][rg]);
      }
  }
  {
    const int r = tid >> 2, d0 = (tid & 3) * 16;
    short8 v0, v1;
#pragma unroll
    for (int j = 0; j < 8; ++j) v0[j] = (short)f2bf(Wt[r][d0 + j]);
#pragma unroll
    for (int j = 0; j < 8; ++j) v1[j] = (short)f2bf(Wt[r][d0 + 8 + j]);
    *(short8*)(&Gh[r][d0]) = v0;
    *(short8*)(&Gh[r][d0 + 8]) = v1;
#pragma unroll
    for (int j = 0; j < 8; ++j) v0[j] = (short)f2bf(Ut[r][d0 + j]);
#pragma unroll
    for (int j = 0; j < 8; ++j) v1[j] = (short)f2bf(Ut[r][d0 + 8 + j]);
    *(short8*)(&Gl[r][d0]) = v0;
    *(short8*)(&Gl[r][d0 + 8]) = v1;
  }
#pragma unroll
  for (int ni = 0; ni < 4; ++ni)
#pragma unroll
    for (int rg = 0; rg < 4; ++rg)
      Ks[16 * w + orow + rg][16 * ni + fr] = f2bf(sreg[ni][rg]);
  __syncthreads();  // (8)

  {
    short8 xs[2];
#pragma unroll
    for (int s = 0; s < 2; ++s) xs[s] = ldb(Ks, xr, s);
    f32x4 accE[4], accF[4];
#pragma unroll
    for (int ni = 0; ni < 4; ++ni) {
      accE[ni] = (f32x4){0.f, 0.f, 0.f, 0.f};
      accF[ni] = (f32x4){0.f, 0.f, 0.f, 0.f};
    }
#pragma unroll
    for (int ni = 0; ni < 4; ++ni)
#pragma unroll
      for (int s = 0; s < 2; ++s) {
        accE[ni] = MFMA(xs[s], ldb(Gh, 16 * ni + fr, s), accE[ni], 0, 0, 0);
        accF[ni] = MFMA(xs[s], ldb(Gl, 16 * ni + fr, s), accF[ni], 0, 0, 0);
      }
#pragma unroll
    for (int ni = 0; ni < 4; ++ni)
#pragma unroll
      for (int rg = 0; rg < 4; ++rg) {
        int r = 16 * w + orow + rg, d = 16 * ni + fr;
        size_t g = gidx(r, d);
        float qv = Qg[g];
        Qg[g] = qv - accE[ni][rg];
        Vg[g] = f2bf(accF[ni][rg]);
      }
  }
}

// ---------------- scalar 64x64 helpers (levelB only) ----------------
__device__ __forceinline__ void store64(float* dst, const float (*src)[65], int tid) {
  for (int i = tid; i < 4096; i += 256) dst[i] = src[i >> 6][i & 63];
}
__device__ __forceinline__ void mm64(const float (*X)[65], const float (*Y)[65],
                                     float (*Dst)[65], const float (*Add)[65], int tid) {
  const int r0 = (tid >> 4) * 4, c0 = (tid & 15) * 4;
  float a[4][4] = {};
  for (int d = 0; d < 64; ++d) {
    float xv[4], yv[4];
#pragma unroll
    for (int i = 0; i < 4; ++i) xv[i] = X[r0 + i][d];
#pragma unroll
    for (int j = 0; j < 4; ++j) yv[j] = Y[d][c0 + j];
#pragma unroll
    for (int i = 0; i < 4; ++i)
#pragma unroll
      for (int j = 0; j < 4; ++j) a[i][j] += xv[i] * yv[j];
  }
  __syncthreads();
#pragma unroll
  for (int i = 0; i < 4; ++i)
#pragma unroll
    for (int j = 0; j < 4; ++j) {
      float v = a[i][j];
      if (Add) v += Add[r0 + i][c0 + j];
      Dst[r0 + i][c0 + j] = v;
    }
  __syncthreads();
}

// ---------------- level A (MFMA, bf16x3) — unchanged ----------------
template<typename PT>
__global__ __launch_bounds__(256) void seq_levelA(const PT* __restrict__ Pg,
    const PT* __restrict__ Rg, float* __restrict__ Psup, float* __restrict__ Rsup) {
  __shared__ __align__(16) float Pa[64][68], Ra[64][68], Ri[64][68];
  __shared__ __align__(16) u16 Pih[64][72], Pil[64][72];
  const int sup = blockIdx.x, h = blockIdx.y, tid = threadIdx.x;
  const int w = tid >> 6, lane = tid & 63;
  const int fr = lane & 15, kq = lane >> 4, orow = kq * 4;
  const int xr = 16 * w + fr;
  const int cbase = sup * SUPW;

  auto upd = [&](float (*St)[68], const float (*Add)[68]) {
    short8 xh[2], xl[2];
#pragma unroll
    for (int s2 = 0; s2 < 2; ++s2) {
      const float* p = &St[xr][32 * s2 + 8 * kq];
#pragma unroll
      for (int j = 0; j < 8; ++j) {
        float v = p[j];
        u16 hb = f2bf(v);
        xh[s2][j] = (short)hb;
        xl[s2][j] = (short)f2bf(v - bf2f(hb));
      }
    }
    f32x4 acc[4];
#pragma unroll
    for (int ni = 0; ni < 4; ++ni) acc[ni] = (f32x4){0.f, 0.f, 0.f, 0.f};
#pragma unroll
    for (int ni = 0; ni < 4; ++ni)
#pragma unroll
      for (int s2 = 0; s2 < 2; ++s2) {
        short8 yh = *(const short8*)(&Pih[16 * ni + fr][32 * s2 + 8 * kq]);
        short8 yl = *(const short8*)(&Pil[16 * ni + fr][32 * s2 + 8 * kq]);
        acc[ni] = MFMA(xh[s2], yh, acc[ni], 0, 0, 0);
        acc[ni] = MFMA(xh[s2], yl, acc[ni], 0, 0, 0);
        acc[ni] = MFMA(xl[s2], yh, acc[ni], 0, 0, 0);
      }
#pragma unroll
    for (int ni = 0; ni < 4; ++ni)
#pragma unroll
      for (int rg = 0; rg < 4; ++rg) {
        float v = acc[ni][rg];
        if (Add) v += Add[16 * w + orow + rg][16 * ni + fr];
        St[16 * w + orow + rg][16 * ni + fr] = v;
      }
  };

  {
    const PT* ps = Pg + ((size_t)cbase * H_ + h) * 4096;
    const PT* rs = Rg + ((size_t)cbase * H_ + h) * 4096;
    for (int i = tid; i < 4096; i += 256) {
      int r = i >> 6, cc = i & 63;
      Pa[r][cc] = ((r == cc) ? 1.f : 0.f) - ldv(ps[i]);
      Ra[r][cc] = ldv(rs[i]);
    }
  }
  float pf[16], rf[16];
  {
    const PT* ps = Pg + ((size_t)(cbase + 1) * H_ + h) * 4096;
    const PT* rs = Rg + ((size_t)(cbase + 1) * H_ + h) * 4096;
#pragma unroll
    for (int k = 0; k < 16; ++k) { int i = tid + k * 256; pf[k] = ldv(ps[i]); rf[k] = ldv(rs[i]); }
  }
  for (int s = 1; s < SUPW; ++s) {
#pragma unroll
    for (int k = 0; k < 16; ++k) {
      int i = tid + k * 256, d = i >> 6, cc = i & 63;
      float v = ((d == cc) ? 1.f : 0.f) - pf[k];
      u16 hb = f2bf(v);
      Pih[cc][d] = hb;
      Pil[cc][d] = f2bf(v - bf2f(hb));
      Ri[d][cc] = rf[k];
    }
    __syncthreads();
    if (s + 1 < SUPW) {
      const PT* ps = Pg + ((size_t)(cbase + s + 1) * H_ + h) * 4096;
      const PT* rs = Rg + ((size_t)(cbase + s + 1) * H_ + h) * 4096;
#pragma unroll
      for (int k = 0; k < 16; ++k) { int i = tid + k * 256; pf[k] = ldv(ps[i]); rf[k] = ldv(rs[i]); }
    }
    upd(Pa, nullptr);
    upd(Ra, Ri);
    __syncthreads();
  }
  for (int i = tid; i < 4096; i += 256) {
    Psup[((size_t)sup * H_ + h) * 4096 + i] = Pa[i >> 6][i & 63];
    Rsup[((size_t)sup * H_ + h) * 4096 + i] = Ra[i >> 6][i & 63];
  }
}

// ---------------- level B: exact fp32 scalar — unchanged ----------------
__global__ __launch_bounds__(256) void seq_levelB(const float* __restrict__ Psup,
    const float* __restrict__ Rsup, float* __restrict__ Msup) {
  __shared__ float Ms[64][65], Pi[64][65], Ri[64][65];
  const int h = blockIdx.x, tid = threadIdx.x;
  for (int i = tid; i < 4096; i += 256) Ms[i >> 6][i & 63] = 0.f;
  float pf[16], rf[16];
  {
    const float* ps = Psup + ((size_t)0 * H_ + h) * 4096;
    const float* rs = Rsup + ((size_t)0 * H_ + h) * 4096;
#pragma unroll
    for (int k = 0; k < 16; ++k) { int i = tid + k * 256; pf[k] = ps[i]; rf[k] = rs[i]; }
  }
  for (int s = 0; s < NSUP; ++s) {
#pragma unroll
    for (int k = 0; k < 16; ++k) {
      int i = tid + k * 256, r = i >> 6, cc = i & 63;
      Pi[r][cc] = pf[k];
      Ri[r][cc] = rf[k];
    }
    store64(Msup + ((size_t)s * H_ + h) * 4096, Ms, tid);
    __syncthreads();
    if (s + 1 < NSUP) {
      const float* ps = Psup + ((size_t)(s + 1) * H_ + h) * 4096;
      const float* rs = Rsup + ((size_t)(s + 1) * H_ + h) * 4096;
#pragma unroll
      for (int k = 0; k < 16; ++k) { int i = tid + k * 256; pf[k] = ps[i]; rf[k] = rs[i]; }
    }
    mm64(Ms, Pi, Ms, Ri, tid);
  }
}

// ---------------- level C (MFMA, bf16x3) — unchanged ----------------
template<typename PT>
__global__ __launch_bounds__(256) void seq_levelC(const PT* __restrict__ Pg,
    PT* __restrict__ Rg, const float* __restrict__ Msup) {
  __shared__ __align__(16) float Ms[64][68], Ri[64][68];
  __shared__ __align__(16) u16 Pih[64][72], Pil[64][72];
  const int sup = blockIdx.x, h = blockIdx.y, tid = threadIdx.x;
  const int w = tid >> 6, lane = tid & 63;
  const int fr = lane & 15, kq = lane >> 4, orow = kq * 4;
  const int xr = 16 * w + fr;

  auto upd = [&](float (*St)[68], const float (*Add)[68]) {
    short8 xh[2], xl[2];
#pragma unroll
    for (int s2 = 0; s2 < 2; ++s2) {
      const float* p = &St[xr][32 * s2 + 8 * kq];
#pragma unroll
      for (int j = 0; j < 8; ++j) {
        float v = p[j];
        u16 hb = f2bf(v);
        xh[s2][j] = (short)hb;
        xl[s2][j] = (short)f2bf(v - bf2f(hb));
      }
    }
    f32x4 acc[4];
#pragma unroll
    for (int ni = 0; ni < 4; ++ni) acc[ni] = (f32x4){0.f, 0.f, 0.f, 0.f};
#pragma unroll
    for (int ni = 0; ni < 4; ++ni)
#pragma unroll
      for (int s2 = 0; s2 < 2; ++s2) {
        short8 yh = *(const short8*)(&Pih[16 * ni + fr][32 * s2 + 8 * kq]);
        short8 yl = *(const short8*)(&Pil[16 * ni + fr][32 * s2 + 8 * kq]);
        acc[ni] = MFMA(xh[s2], yh, acc[ni], 0, 0, 0);
        acc[ni] = MFMA(xh[s2], yl, acc[ni], 0, 0, 0);
        acc[ni] = MFMA(xl[s2], yh, acc[ni], 0, 0, 0);
      }
#pragma unroll
    for (int ni = 0; ni < 4; ++ni)
#pragma unroll
      for (int rg = 0; rg < 4; ++rg) {
        float v = acc[ni][rg];
        if (Add) v += Add[16 * w + orow + rg][16 * ni + fr];
        St[16 * w + orow + rg][16 * ni + fr] = v;
      }
  };

  for (int i = tid; i < 4096; i += 256)
    Ms[i >> 6][i & 63] = Msup[((size_t)sup * H_ + h) * 4096 + i];
  float pf[16], rf[16];
  {
    const size_t slice = ((size_t)(sup * SUPW) * H_ + h) * 4096;
#pragma unroll
    for (int k = 0; k < 16; ++k) { int i = tid + k * 256; pf[k] = ldv(Pg[slice + i]); rf[k] = ldv(Rg[slice + i]); }
  }
  for (int s = 0; s < SUPW; ++s) {
    const size_t slice = ((size_t)(sup * SUPW + s) * H_ + h) * 4096;
#pragma unroll
    for (int k = 0; k < 16; ++k) {
      int i = tid + k * 256, d = i >> 6, cc = i & 63;
      float v = ((d == cc) ? 1.f : 0.f) - pf[k];
      u16 hb = f2bf(v);
      Pih[cc][d] = hb;
      Pil[cc][d] = f2bf(v - bf2f(hb));
      Ri[d][cc] = rf[k];
    }
    for (int i = tid; i < 4096; i += 256) stv(&Rg[slice + i], Ms[i >> 6][i & 63]);
    __syncthreads();
    if (s + 1 < SUPW) {
      const size_t sl2 = ((size_t)(sup * SUPW + s + 1) * H_ + h) * 4096;
#pragma unroll
      for (int k = 0; k < 16; ++k) { int i = tid + k * 256; pf[k] = ldv(Pg[sl2 + i]); rf[k] = ldv(Rg[sl2 + i]); }
    }
    upd(Ms, Ri);
    __syncthreads();
  }
}

// ---------------- phase 3: attn = E*M0^T + F — unchanged ----------------
template<typename PT>
__global__ __launch_bounds__(256) void phase3_kernel(
    const float* __restrict__ Eg, const u16* __restrict__ Fg,
    const PT* __restrict__ Mcg, u16* __restrict__ attn) {
  __shared__ float Es[64][65], Ms[64][65];
  const int c = blockIdx.x, h = blockIdx.y, tid = threadIdx.x;
  for (int i = tid; i < 4096; i += 256) {
    int r = i >> 6, d = i & 63, t = r >> 2, b = r & 3;
    size_t g = ((size_t)b * S_ + (size_t)c * CHUNK + t) * D_ + h * 64 + d;
    Es[r][d] = Eg[g];
    Ms[i >> 6][i & 63] = ldv(Mcg[((size_t)c * H_ + h) * 4096 + i]);
  }
  __syncthreads();
  const int r0 = (tid >> 4) * 4, d0 = (tid & 15) * 4;
  float a[4][4] = {};
  for (int k = 0; k < 64; ++k) {
    float ev[4], mv[4];
#pragma unroll
    for (int i = 0; i < 4; ++i) ev[i] = Es[r0 + i][k];
#pragma unroll
    for (int j = 0; j < 4; ++j) mv[j] = Ms[d0 + j][k];
#pragma unroll
    for (int i = 0; i < 4; ++i)
#pragma unroll
      for (int j = 0; j < 4; ++j) a[i][j] += ev[i] * mv[j];
  }
#pragma unroll
  for (int i = 0; i < 4; ++i)
#pragma unroll
    for (int j = 0; j < 4; ++j) {
      int r = r0 + i, d = d0 + j, t = r >> 2, b = r & 3;
      size_t g = ((size_t)b * S_ + (size_t)c * CHUNK + t) * D_ + h * 64 + d;
      attn[g] = f2bf(a[i][j] + bf2f(Fg[g]));
    }
}

// ---------------- launch ----------------
extern "C" void kernel_launch(void* const* d_in, const int* in_sizes, int n_in,
                              void* d_out, int out_size, void* d_ws, size_t ws_size,
                              hipStream_t stream) {
  (void)in_sizes; (void)n_in; (void)out_size;
  const float* x  = (const float*)d_in[0];
  const float* Wq = (const float*)d_in[1];
  const float* Wk = (const float*)d_in[2];
  const float* Wv = (const float*)d_in[3];
  const float* Wo = (const float*)d_in[4];
  float* out = (float*)d_out;

  char* w = (char*)d_ws;
  const size_t MB = 1024 * 1024;
  u16* Kbf = (u16*)w;
  u16* Vbf = (u16*)(w + 32 * MB);
  u16* xh  = (u16*)(w + 64 * MB);
  const bool big = ws_size >= 192 * MB;
  void* Preg = (void*)(w + 64 * MB);
  void* Rreg = big ? (void*)(w + 128 * MB) : (void*)(w + 96 * MB);
  float* Psup = (float*)w;
  float* Rsup = (float*)(w + 4 * MB);
  float* Msup = (float*)(w + 8 * MB);
  u16* attn = (u16*)Preg;
  u16* Wsp = (u16*)(w + 128 * MB);  // hi-only: q +0, k +1M, v +2M (u16); o reuses +0

  const size_t DSZ = (size_t)B_ * S_ * D_;  // 16777216
  cvt_hi_kernel<<<2048, 256, 0, stream>>>(x, xh, (int)(DSZ / 4));

  dim3 gg(128, 4);  // 128x256 tiles over 16384 x 1024
  if (big) {
    cvt_hi_kernel<<<512, 256, 0, stream>>>(Wq, Wsp + 0 * 1048576u, 262144);
    cvt_hi_kernel<<<512, 256, 0, stream>>>(Wk, Wsp + 1 * 1048576u, 262144);
    cvt_hi_kernel<<<512, 256, 0, stream>>>(Wv, Wsp + 2 * 1048576u, 262144);
    gemm_axw<1, float><<<gg, 256, 0, stream>>>(xh, Wsp + 0 * 1048576u, out, 16384, 1024, 1024);
    gemm_axw<1, u16><<<gg, 256, 0, stream>>>(xh, Wsp + 1 * 1048576u, Kbf, 16384, 1024, 1024);
    gemm_axw<1, u16><<<gg, 256, 0, stream>>>(xh, Wsp + 2 * 1048576u, Vbf, 16384, 1024, 1024);
    float* P = (float*)Preg; float* R = (float*)Rreg;
    phase1_kernel<float><<<dim3(NCHUNK, H_), 256, 0, stream>>>(out, Kbf, Vbf, P, R);
    seq_levelA<float><<<dim3(NSUP, H_), 256, 0, stream>>>(P, R, Psup, Rsup);
    seq_levelB<<<dim3(H_), 256, 0, stream>>>(Psup, Rsup, Msup);
    seq_levelC<float><<<dim3(NSUP, H_), 256, 0, stream>>>(P, R, Msup);
    phase3_kernel<float><<<dim3(NCHUNK, H_), 256, 0, stream>>>(out, Vbf, R, attn);
    cvt_hi_kernel<<<512, 256, 0, stream>>>(Wo, Wsp + 0 * 1048576u, 262144);
    gemm_axw<1, float><<<gg, 256, 0, stream>>>(attn, Wsp + 0 * 1048576u, out, 16384, 1024, 1024);
  } else {
    gemm_axw<0, float><<<gg, 256, 0, stream>>>(xh, Wq, out, 16384, 1024, 1024);
    gemm_axw<0, u16><<<gg, 256, 0, stream>>>(xh, Wk, Kbf, 16384, 1024, 1024);
    gemm_axw<0, u16><<<gg, 256, 0, stream>>>(xh, Wv, Vbf, 16384, 1024, 1024);
    u16* P = (u16*)Preg; u16* R = (u16*)Rreg;
    phase1_kernel<u16><<<dim3(NCHUNK, H_), 256, 0, stream>>>(out, Kbf, Vbf, P, R);
    seq_levelA<u16><<<dim3(NSUP, H_), 256, 0, stream>>>(P, R, Psup, Rsup);
    seq_levelB<<<dim3(H_), 256, 0, stream>>>(Psup, Rsup, Msup);
    seq_levelC<u16><<<dim3(NSUP, H_), 256, 0, stream>>>(P, R, Msup);
    phase3_kernel<u16><<<dim3(NCHUNK, H_), 256, 0, stream>>>(out, Vbf, R, attn);
    gemm_axw<0, float><<<gg, 256, 0, stream>>>(attn, Wo, out, 16384, 1024, 1024);
  }
}

// Round 14
// 547.389 us; speedup vs baseline: 1.0668x; 1.0668x over previous
//
#include <hip/hip_runtime.h>

// L2RegressionAttention — chunked WY-transform.
// r14: consolidation. GEMM = r12 optimum (128x128, 2-buf drain, plain block
// order -> A-panel L2-resident; 5 blk/CU TLP beats deeper pipelines/tiles per
// r11/r13 A/B). phase1: sq1 single-pass (N^2 is bf16-stored; corrections were
// below storage rounding) and Xs buffer removed. W converts merged (1 launch).
// B=4, S=4096, D=1024, H=16, hd=64, eta = 0.1/4 = 0.025.

typedef unsigned short u16;
typedef __attribute__((ext_vector_type(8))) short short8;
typedef __attribute__((ext_vector_type(4))) float f32x4;

#define B_ 4
#define S_ 4096
#define D_ 1024
#define H_ 16
#define CHUNK 16
#define NCHUNK 256
#define SUPW 16
#define NSUP 16
#define ETA 0.025f

__device__ __forceinline__ u16 f2bf(float f) {
  unsigned u = __builtin_bit_cast(unsigned, f);
  u += 0x7fffu + ((u >> 16) & 1u);
  return (u16)(u >> 16);
}
__device__ __forceinline__ float bf2f(u16 s) {
  unsigned u = ((unsigned)s) << 16;
  return __builtin_bit_cast(float, u);
}
__device__ __forceinline__ float ldv(float v) { return v; }
__device__ __forceinline__ float ldv(u16 v) { return bf2f(v); }
__device__ __forceinline__ void stv(float* p, float v) { *p = v; }
__device__ __forceinline__ void stv(u16* p, float v) { *p = f2bf(v); }

#define MFMA __builtin_amdgcn_mfma_f32_16x16x32_bf16

__device__ __forceinline__ void gload16(const void* g, void* l) {
  __builtin_amdgcn_global_load_lds(
      (__attribute__((address_space(1))) void*)g,
      (__attribute__((address_space(3))) void*)l, 16, 0, 0);
}

// ---------------- fp32 -> bf16 hi-only convert ----------------
__global__ void cvt_hi_kernel(const float* __restrict__ x, u16* __restrict__ hi, int n4) {
  int i = blockIdx.x * blockDim.x + threadIdx.x;
  int stride = gridDim.x * blockDim.x;
  for (; i < n4; i += stride) {
    float4 v = ((const float4*)x)[i];
    ushort4 h;
    h.x = f2bf(v.x); h.y = f2bf(v.y); h.z = f2bf(v.z); h.w = f2bf(v.w);
    ((ushort4*)hi)[i] = h;
  }
}

// three weight matrices in one launch (blockIdx.y selects)
__global__ void cvt_hi3_kernel(const float* __restrict__ a, const float* __restrict__ b,
                               const float* __restrict__ c, u16* __restrict__ o0,
                               u16* __restrict__ o1, u16* __restrict__ o2, int n4) {
  const float* src = (blockIdx.y == 0) ? a : (blockIdx.y == 1) ? b : c;
  u16* dst = (blockIdx.y == 0) ? o0 : (blockIdx.y == 1) ? o1 : o2;
  int i = blockIdx.x * blockDim.x + threadIdx.x;
  int stride = gridDim.x * blockDim.x;
  for (; i < n4; i += stride) {
    float4 v = ((const float4*)src)[i];
    ushort4 h;
    h.x = f2bf(v.x); h.y = f2bf(v.y); h.z = f2bf(v.z); h.w = f2bf(v.w);
    ((ushort4*)dst)[i] = h;
  }
}

// ---------------- GEMM: C[M][N] = A * B^T (r12 optimum) ----------------
template<int BPRE, typename OutT>
__global__ __launch_bounds__(256) void gemm_axw(
    const u16* __restrict__ Ahg, const void* __restrict__ Bhp,
    OutT* __restrict__ C, int M, int N, int K) {
  __shared__ __align__(16) u16 Ahs[2][128][32];
  __shared__ __align__(16) u16 Bhs[2][128][32];
  const int tid = threadIdx.x, w = tid >> 6, lane = tid & 63;
  const int bm = blockIdx.x * 128, bn = blockIdx.y * 128;
  const int wm = (w >> 1) * 64, wn = (w & 1) * 64;
  const int fr = lane & 15, kb = lane >> 4;
  const int lrow = lane >> 2, lcol = (lane & 3) * 8;

  auto stage = [&](int buf, int k0) {
    {
      const size_t rb = (size_t)(bm + w * 32 + lrow) * K + k0 + lcol;
      gload16(Ahg + rb, &Ahs[buf][w * 32][0]);
      gload16(Ahg + rb + (size_t)16 * K, &Ahs[buf][w * 32 + 16][0]);
    }
    if constexpr (BPRE) {
      const u16* Bhg = (const u16*)Bhp;
      const size_t rb = (size_t)(bn + w * 32 + lrow) * K + k0 + lcol;
      gload16(Bhg + rb, &Bhs[buf][w * 32][0]);
      gload16(Bhg + rb + (size_t)16 * K, &Bhs[buf][w * 32 + 16][0]);
    } else {
      const float* Bm = (const float*)Bhp;
#pragma unroll
      for (int i2 = 0; i2 < 4; ++i2) {
        int e = tid + i2 * 256, r = e >> 3, sg = (e & 7) * 4;
        float4 v = *(const float4*)(&Bm[(size_t)(bn + r) * K + k0 + sg]);
        ushort4 hq;
        hq.x = f2bf(v.x); hq.y = f2bf(v.y); hq.z = f2bf(v.z); hq.w = f2bf(v.w);
        *(ushort4*)(&Bhs[buf][r][sg]) = hq;
      }
    }
  };
  auto compute = [&](int buf, f32x4 (*acc)[4]) {
    short8 ah[4], bh[4];
#pragma unroll
    for (int mi = 0; mi < 4; ++mi)
      ah[mi] = *(const short8*)(&Ahs[buf][wm + mi * 16 + fr][kb * 8]);
#pragma unroll
    for (int ni = 0; ni < 4; ++ni)
      bh[ni] = *(const short8*)(&Bhs[buf][wn + ni * 16 + fr][kb * 8]);
#pragma unroll
    for (int mi = 0; mi < 4; ++mi)
#pragma unroll
      for (int ni = 0; ni < 4; ++ni)
        acc[mi][ni] = MFMA(ah[mi], bh[ni], acc[mi][ni], 0, 0, 0);
  };

  f32x4 acc[4][4];
#pragma unroll
  for (int i = 0; i < 4; ++i)
#pragma unroll
    for (int j = 0; j < 4; ++j) acc[i][j] = (f32x4){0.f, 0.f, 0.f, 0.f};

  const int nt = K >> 5;
  stage(0, 0);
  asm volatile("s_waitcnt vmcnt(0)" ::: "memory");
  __syncthreads();
  int cur = 0;
  for (int t = 0; t < nt; ++t) {
    if (t + 1 < nt) stage(cur ^ 1, (t + 1) * 32);
    compute(cur, acc);
    asm volatile("s_waitcnt vmcnt(0)" ::: "memory");
    __syncthreads();
    cur ^= 1;
  }
  const int fc = lane & 15, fr4 = (lane >> 4) * 4;
#pragma unroll
  for (int mi = 0; mi < 4; ++mi)
#pragma unroll
    for (int ni = 0; ni < 4; ++ni) {
      int gm = bm + wm + mi * 16 + fr4;
      int gn = bn + wn + ni * 16 + fc;
#pragma unroll
      for (int rg = 0; rg < 4; ++rg)
        stv(&C[(size_t)(gm + rg) * N + gn], acc[mi][ni][rg]);
    }
}

// ---------------- phase 1 (MFMA, pre-masked N, fused U/W, 1-pass sq1) ----------------
template<typename PT>
__global__ __launch_bounds__(256) void phase1_kernel(
    float* __restrict__ Qg, const u16* __restrict__ Kg, u16* __restrict__ Vg,
    PT* __restrict__ Pg, PT* __restrict__ Rg) {
  __shared__ __align__(16) u16 Ks[64][72];
  __shared__ __align__(16) u16 KsT[64][72];
  __shared__ __align__(16) u16 Gh[64][72];
  __shared__ __align__(16) u16 Gl[64][72];
  __shared__ __align__(16) float Ut[64][68];
  __shared__ __align__(16) float Wt[64][68];

  const int c = blockIdx.x, h = blockIdx.y, tid = threadIdx.x;
  const int w = tid >> 6, lane = tid & 63;
  const int fr = lane & 15, kq = lane >> 4, orow = kq * 4;
  const int xr = 16 * w + fr;

  auto gidx = [&](int r, int d) -> size_t {
    return ((size_t)(r & 3) * S_ + (size_t)c * CHUNK + (r >> 2)) * D_ + h * 64 + d;
  };
  auto ldb = [&](const u16 (*M)[72], int row, int s) -> short8 {
    return *(const short8*)(&M[row][32 * s + 8 * kq]);
  };
  auto ldf = [&](const float (*M)[68], int row, int s, short8& hh, short8& ll) {
    const float* p = &M[row][32 * s + 8 * kq];
#pragma unroll
    for (int j = 0; j < 8; ++j) {
      float v = p[j];
      u16 hb = f2bf(v);
      hh[j] = (short)hb;
      ll[j] = (short)f2bf(v - bf2f(hb));
    }
  };
  auto ldfh = [&](const float (*M)[68], int row, int s) -> short8 {
    const float* p = &M[row][32 * s + 8 * kq];
    short8 hh;
#pragma unroll
    for (int j = 0; j < 8; ++j) hh[j] = (short)f2bf(p[j]);
    return hh;
  };

  // ---- ph0: load K (+K^T), V; states ----
  for (int i = tid; i < 4096; i += 256) {
    int r = i >> 6, d = i & 63;
    size_t g = gidx(r, d);
    u16 kraw = Kg[g];
    Ks[r][d] = kraw;
    KsT[d][r] = kraw;
    Wt[d][r] = ETA * bf2f(kraw);
    Ut[d][r] = ETA * bf2f(Vg[g]);
  }
  __syncthreads();  // (1)

  // ---- G accumulate (regs) ----
  f32x4 gacc[4];
#pragma unroll
  for (int ni = 0; ni < 4; ++ni) gacc[ni] = (f32x4){0.f, 0.f, 0.f, 0.f};
  {
    short8 xf[2];
#pragma unroll
    for (int s = 0; s < 2; ++s) xf[s] = ldb(Ks, xr, s);
#pragma unroll
    for (int ni = 0; ni < 4; ++ni)
#pragma unroll
      for (int s = 0; s < 2; ++s)
        gacc[ni] = MFMA(xf[s], ldb(Ks, 16 * ni + fr, s), gacc[ni], 0, 0, 0);
  }

  // ---- S = Q K^T -> sreg (early) ----
  float sreg[4][4];
  {
    short8 xh[2], xl[2];
#pragma unroll
    for (int s = 0; s < 2; ++s) {
      const float* qp = &Qg[gidx(xr, 32 * s + 8 * kq)];
#pragma unroll
      for (int j = 0; j < 8; ++j) {
        float v = qp[j];
        u16 hb = f2bf(v);
        xh[s][j] = (short)hb;
        xl[s][j] = (short)f2bf(v - bf2f(hb));
      }
    }
    f32x4 acc[4];
#pragma unroll
    for (int ni = 0; ni < 4; ++ni) acc[ni] = (f32x4){0.f, 0.f, 0.f, 0.f};
#pragma unroll
    for (int ni = 0; ni < 4; ++ni)
#pragma unroll
      for (int s = 0; s < 2; ++s) {
        short8 yf = ldb(Ks, 16 * ni + fr, s);
        acc[ni] = MFMA(xh[s], yf, acc[ni], 0, 0, 0);
        acc[ni] = MFMA(xl[s], yf, acc[ni], 0, 0, 0);
      }
#pragma unroll
    for (int ni = 0; ni < 4; ++ni)
#pragma unroll
      for (int rg = 0; rg < 4; ++rg) {
        int r = 16 * w + orow + rg, cc = 16 * ni + fr;
        sreg[ni][rg] = ((r >> 2) >= (cc >> 2)) ? acc[ni][rg] : 0.f;
      }
  }
  __syncthreads();  // (1b)

  // ---- write NL (Gh/Gl) and NU-h (Ks), masked once ----
#pragma unroll
  for (int ni = 0; ni < 4; ++ni)
#pragma unroll
    for (int rg = 0; rg < 4; ++rg) {
      float v = -ETA * gacc[ni][rg];
      u16 hb = f2bf(v);
      u16 lb = f2bf(v - bf2f(hb));
      int rr = 16 * w + orow + rg, cc = 16 * ni + fr;
      bool low = (rr >> 2) > (cc >> 2);
      u16 hm = low ? hb : (u16)0, lm = low ? lb : (u16)0;
      Gh[rr][cc] = hm;
      Gl[rr][cc] = lm;
      Ks[cc][rr] = hm;   // NU-h (symmetry)
    }
  __syncthreads();  // (2)

  // fused state update (3-pass h/l, shared Y)
  {
    short8 uh[2], ul[2], wh[2], wl[2];
#pragma unroll
    for (int s = 0; s < 2; ++s) { ldf(Ut, xr, s, uh[s], ul[s]); ldf(Wt, xr, s, wh[s], wl[s]); }
    f32x4 aU[4], aW[4];
#pragma unroll
    for (int ni = 0; ni < 4; ++ni) { aU[ni] = (f32x4){0.f,0.f,0.f,0.f}; aW[ni] = (f32x4){0.f,0.f,0.f,0.f}; }
#pragma unroll
    for (int ni = 0; ni < 4; ++ni)
#pragma unroll
      for (int s = 0; s < 2; ++s) {
        short8 yh = ldb(Gh, 16 * ni + fr, s);
        short8 yl = ldb(Gl, 16 * ni + fr, s);
        aU[ni] = MFMA(uh[s], yh, aU[ni], 0, 0, 0);
        aU[ni] = MFMA(uh[s], yl, aU[ni], 0, 0, 0);
        aU[ni] = MFMA(ul[s], yh, aU[ni], 0, 0, 0);
        aW[ni] = MFMA(wh[s], yh, aW[ni], 0, 0, 0);
        aW[ni] = MFMA(wh[s], yl, aW[ni], 0, 0, 0);
        aW[ni] = MFMA(wl[s], yh, aW[ni], 0, 0, 0);
      }
#pragma unroll
    for (int ni = 0; ni < 4; ++ni)
#pragma unroll
      for (int rg = 0; rg < 4; ++rg) {
        Ut[16 * w + orow + rg][16 * ni + fr] += aU[ni][rg];
        Wt[16 * w + orow + rg][16 * ni + fr] += aW[ni][rg];
      }
  }
  auto appSf = [&](const u16 (*Np)[72]) {
    short8 xu[2], xw[2];
#pragma unroll
    for (int s = 0; s < 2; ++s) { xu[s] = ldfh(Ut, xr, s); xw[s] = ldfh(Wt, xr, s); }
    f32x4 aU[4], aW[4];
#pragma unroll
    for (int ni = 0; ni < 4; ++ni) { aU[ni] = (f32x4){0.f,0.f,0.f,0.f}; aW[ni] = (f32x4){0.f,0.f,0.f,0.f}; }
#pragma unroll
    for (int ni = 0; ni < 4; ++ni)
#pragma unroll
      for (int s = 0; s < 2; ++s) {
        short8 yf = ldb(Np, 16 * ni + fr, s);
        aU[ni] = MFMA(xu[s], yf, aU[ni], 0, 0, 0);
        aW[ni] = MFMA(xw[s], yf, aW[ni], 0, 0, 0);
      }
#pragma unroll
    for (int ni = 0; ni < 4; ++ni)
#pragma unroll
      for (int rg = 0; rg < 4; ++rg) {
        Ut[16 * w + orow + rg][16 * ni + fr] += aU[ni][rg];
        Wt[16 * w + orow + rg][16 * ni + fr] += aW[ni][rg];
      }
  };

  // ---- sq1 single-pass: N^2 = NLh x (NU-h)^T -> Ks, N^2T -> Gh ----
  {
    f32x4 sq[4];
#pragma unroll
    for (int ni = 0; ni < 4; ++ni) sq[ni] = (f32x4){0.f, 0.f, 0.f, 0.f};
    short8 xh[2];
#pragma unroll
    for (int s = 0; s < 2; ++s) xh[s] = ldb(Gh, xr, s);
#pragma unroll
    for (int ni = 0; ni < 4; ++ni)
#pragma unroll
      for (int s = 0; s < 2; ++s)
        sq[ni] = MFMA(xh[s], ldb(Ks, 16 * ni + fr, s), sq[ni], 0, 0, 0);
    __syncthreads();  // (3)
#pragma unroll
    for (int ni = 0; ni < 4; ++ni)
#pragma unroll
      for (int rg = 0; rg < 4; ++rg) {
        u16 b = f2bf(sq[ni][rg]);
        int rr = 16 * w + orow + rg, cc = 16 * ni + fr;
        Ks[rr][cc] = b;   // N^2
        Gh[cc][rr] = b;   // N^2T
      }
  }
  __syncthreads();  // (4)

  appSf(Ks);  // app2
  {
    f32x4 sq[4];
#pragma unroll
    for (int ni = 0; ni < 4; ++ni) sq[ni] = (f32x4){0.f, 0.f, 0.f, 0.f};
    short8 xf[2];
#pragma unroll
    for (int s = 0; s < 2; ++s) xf[s] = ldb(Ks, xr, s);
#pragma unroll
    for (int ni = 0; ni < 4; ++ni)
#pragma unroll
      for (int s = 0; s < 2; ++s)
        sq[ni] = MFMA(xf[s], ldb(Gh, 16 * ni + fr, s), sq[ni], 0, 0, 0);
    __syncthreads();  // (5)
#pragma unroll
    for (int ni = 0; ni < 4; ++ni)
#pragma unroll
      for (int rg = 0; rg < 4; ++rg) {
        u16 b = f2bf(sq[ni][rg]);
        int rr = 16 * w + orow + rg, cc = 16 * ni + fr;
        Gl[rr][cc] = b;   // N^4
        Ks[cc][rr] = b;   // N^4T
      }
  }
  __syncthreads();  // (6)

  appSf(Gl);  // app3
  {
    f32x4 sq[4];
#pragma unroll
    for (int ni = 0; ni < 4; ++ni) sq[ni] = (f32x4){0.f, 0.f, 0.f, 0.f};
    short8 xf[2];
#pragma unroll
    for (int s = 0; s < 2; ++s) xf[s] = ldb(Gl, xr, s);
#pragma unroll
    for (int ni = 0; ni < 4; ++ni)
#pragma unroll
      for (int s = 0; s < 2; ++s)
        sq[ni] = MFMA(xf[s], ldb(Ks, 16 * ni + fr, s), sq[ni], 0, 0, 0);
#pragma unroll
    for (int ni = 0; ni < 4; ++ni)
#pragma unroll
      for (int rg = 0; rg < 4; ++rg)
        Gh[16 * w + orow + rg][16 * ni + fr] = f2bf(sq[ni][rg]);  // N^8
  }
  __syncthreads();  // (7)

  appSf(Gh);  // app4
  __syncthreads();  // (7b)

  // ---- P/R fused (shared KsT Y-frags) ----
  const size_t base = ((size_t)c * H_ + h) * 4096;
  {
    short8 wh[2], wl[2], uh[2], ul[2];
#pragma unroll
    for (int s = 0; s < 2; ++s) { ldf(Wt, xr, s, wh[s], wl[s]); ldf(Ut, xr, s, uh[s], ul[s]); }
    f32x4 aP[4], aR[4];
#pragma unroll
    for (int ni = 0; ni < 4; ++ni) { aP[ni] = (f32x4){0.f,0.f,0.f,0.f}; aR[ni] = (f32x4){0.f,0.f,0.f,0.f}; }
#pragma unroll
    for (int ni = 0; ni < 4; ++ni)
#pragma unroll
      for (int s = 0; s < 2; ++s) {
        short8 yf = ldb(KsT, 16 * ni + fr, s);
        aP[ni] = MFMA(wh[s], yf, aP[ni], 0, 0, 0);
        aP[ni] = MFMA(wl[s], yf, aP[ni], 0, 0, 0);
        aR[ni] = MFMA(uh[s], yf, aR[ni], 0, 0, 0);
        aR[ni] = MFMA(ul[s], yf, aR[ni], 0, 0, 0);
      }
#pragma unroll
    for (int ni = 0; ni < 4; ++ni)
#pragma unroll
      for (int rg = 0; rg < 4; ++rg) {
        stv(&Pg[base + (16 * w + orow + rg) * 64 + 16 * ni + fr], aP[ni][rg]);
        stv(&Rg[base + (16 * w + orow + rg) * 64 + 16 * ni + fr], aR[ni][rg]);
      }
  }
  // single-bf16 conversions: Wb->Gh (N^8 dead), Ub->Gl (N^4 dead)
  {
    const int r = tid >> 2, d0 = (tid & 3) * 16;
    short8 v0, v1;
#pragma unroll
    for (int j = 0; j < 8; ++j) v0[j] = (short)f2bf(Wt[r][d0 + j]);
#pragma unroll
    for (int j = 0; j < 8; ++j) v1[j] = (short)f2bf(Wt[r][d0 + 8 + j]);
    *(short8*)(&Gh[r][d0]) = v0;
    *(short8*)(&Gh[r][d0 + 8]) = v1;
#pragma unroll
    for (int j = 0; j < 8; ++j) v0[j] = (short)f2bf(Ut[r][d0 + j]);
#pragma unroll
    for (int j = 0; j < 8; ++j) v1[j] = (short)f2bf(Ut[r][d0 + 8 + j]);
    *(short8*)(&Gl[r][d0]) = v0;
    *(short8*)(&Gl[r][d0 + 8]) = v1;
  }
#pragma unroll
  for (int ni = 0; ni < 4; ++ni)
#pragma unroll
    for (int rg = 0; rg < 4; ++rg)
      Ks[16 * w + orow + rg][16 * ni + fr] = f2bf(sreg[ni][rg]);  // Sm
  __syncthreads();  // (8)

  // ---- E = Q - Sm*Wb ; F = Sm*Ub (single-pass) ----
  {
    short8 xs[2];
#pragma unroll
    for (int s = 0; s < 2; ++s) xs[s] = ldb(Ks, xr, s);
    f32x4 accE[4], accF[4];
#pragma unroll
    for (int ni = 0; ni < 4; ++ni) {
      accE[ni] = (f32x4){0.f, 0.f, 0.f, 0.f};
      accF[ni] = (f32x4){0.f, 0.f, 0.f, 0.f};
    }
#pragma unroll
    for (int ni = 0; ni < 4; ++ni)
#pragma unroll
      for (int s = 0; s < 2; ++s) {
        accE[ni] = MFMA(xs[s], ldb(Gh, 16 * ni + fr, s), accE[ni], 0, 0, 0);
        accF[ni] = MFMA(xs[s], ldb(Gl, 16 * ni + fr, s), accF[ni], 0, 0, 0);
      }
#pragma unroll
    for (int ni = 0; ni < 4; ++ni)
#pragma unroll
      for (int rg = 0; rg < 4; ++rg) {
        int r = 16 * w + orow + rg, d = 16 * ni + fr;
        size_t g = gidx(r, d);
        float qv = Qg[g];
        Qg[g] = qv - accE[ni][rg];
        Vg[g] = f2bf(accF[ni][rg]);
      }
  }
}

// ---------------- scalar 64x64 helpers (levelB only) ----------------
__device__ __forceinline__ void store64(float* dst, const float (*src)[65], int tid) {
  for (int i = tid; i < 4096; i += 256) dst[i] = src[i >> 6][i & 63];
}
__device__ __forceinline__ void mm64(const float (*X)[65], const float (*Y)[65],
                                     float (*Dst)[65], const float (*Add)[65], int tid) {
  const int r0 = (tid >> 4) * 4, c0 = (tid & 15) * 4;
  float a[4][4] = {};
  for (int d = 0; d < 64; ++d) {
    float xv[4], yv[4];
#pragma unroll
    for (int i = 0; i < 4; ++i) xv[i] = X[r0 + i][d];
#pragma unroll
    for (int j = 0; j < 4; ++j) yv[j] = Y[d][c0 + j];
#pragma unroll
    for (int i = 0; i < 4; ++i)
#pragma unroll
      for (int j = 0; j < 4; ++j) a[i][j] += xv[i] * yv[j];
  }
  __syncthreads();
#pragma unroll
  for (int i = 0; i < 4; ++i)
#pragma unroll
    for (int j = 0; j < 4; ++j) {
      float v = a[i][j];
      if (Add) v += Add[r0 + i][c0 + j];
      Dst[r0 + i][c0 + j] = v;
    }
  __syncthreads();
}

// ---------------- level A (MFMA, bf16x3) — unchanged ----------------
template<typename PT>
__global__ __launch_bounds__(256) void seq_levelA(const PT* __restrict__ Pg,
    const PT* __restrict__ Rg, float* __restrict__ Psup, float* __restrict__ Rsup) {
  __shared__ __align__(16) float Pa[64][68], Ra[64][68], Ri[64][68];
  __shared__ __align__(16) u16 Pih[64][72], Pil[64][72];
  const int sup = blockIdx.x, h = blockIdx.y, tid = threadIdx.x;
  const int w = tid >> 6, lane = tid & 63;
  const int fr = lane & 15, kq = lane >> 4, orow = kq * 4;
  const int xr = 16 * w + fr;
  const int cbase = sup * SUPW;

  auto upd = [&](float (*St)[68], const float (*Add)[68]) {
    short8 xh[2], xl[2];
#pragma unroll
    for (int s2 = 0; s2 < 2; ++s2) {
      const float* p = &St[xr][32 * s2 + 8 * kq];
#pragma unroll
      for (int j = 0; j < 8; ++j) {
        float v = p[j];
        u16 hb = f2bf(v);
        xh[s2][j] = (short)hb;
        xl[s2][j] = (short)f2bf(v - bf2f(hb));
      }
    }
    f32x4 acc[4];
#pragma unroll
    for (int ni = 0; ni < 4; ++ni) acc[ni] = (f32x4){0.f, 0.f, 0.f, 0.f};
#pragma unroll
    for (int ni = 0; ni < 4; ++ni)
#pragma unroll
      for (int s2 = 0; s2 < 2; ++s2) {
        short8 yh = *(const short8*)(&Pih[16 * ni + fr][32 * s2 + 8 * kq]);
        short8 yl = *(const short8*)(&Pil[16 * ni + fr][32 * s2 + 8 * kq]);
        acc[ni] = MFMA(xh[s2], yh, acc[ni], 0, 0, 0);
        acc[ni] = MFMA(xh[s2], yl, acc[ni], 0, 0, 0);
        acc[ni] = MFMA(xl[s2], yh, acc[ni], 0, 0, 0);
      }
#pragma unroll
    for (int ni = 0; ni < 4; ++ni)
#pragma unroll
      for (int rg = 0; rg < 4; ++rg) {
        float v = acc[ni][rg];
        if (Add) v += Add[16 * w + orow + rg][16 * ni + fr];
        St[16 * w + orow + rg][16 * ni + fr] = v;
      }
  };

  {
    const PT* ps = Pg + ((size_t)cbase * H_ + h) * 4096;
    const PT* rs = Rg + ((size_t)cbase * H_ + h) * 4096;
    for (int i = tid; i < 4096; i += 256) {
      int r = i >> 6, cc = i & 63;
      Pa[r][cc] = ((r == cc) ? 1.f : 0.f) - ldv(ps[i]);
      Ra[r][cc] = ldv(rs[i]);
    }
  }
  float pf[16], rf[16];
  {
    const PT* ps = Pg + ((size_t)(cbase + 1) * H_ + h) * 4096;
    const PT* rs = Rg + ((size_t)(cbase + 1) * H_ + h) * 4096;
#pragma unroll
    for (int k = 0; k < 16; ++k) { int i = tid + k * 256; pf[k] = ldv(ps[i]); rf[k] = ldv(rs[i]); }
  }
  for (int s = 1; s < SUPW; ++s) {
#pragma unroll
    for (int k = 0; k < 16; ++k) {
      int i = tid + k * 256, d = i >> 6, cc = i & 63;
      float v = ((d == cc) ? 1.f : 0.f) - pf[k];
      u16 hb = f2bf(v);
      Pih[cc][d] = hb;
      Pil[cc][d] = f2bf(v - bf2f(hb));
      Ri[d][cc] = rf[k];
    }
    __syncthreads();
    if (s + 1 < SUPW) {
      const PT* ps = Pg + ((size_t)(cbase + s + 1) * H_ + h) * 4096;
      const PT* rs = Rg + ((size_t)(cbase + s + 1) * H_ + h) * 4096;
#pragma unroll
      for (int k = 0; k < 16; ++k) { int i = tid + k * 256; pf[k] = ldv(ps[i]); rf[k] = ldv(rs[i]); }
    }
    upd(Pa, nullptr);
    upd(Ra, Ri);
    __syncthreads();
  }
  for (int i = tid; i < 4096; i += 256) {
    Psup[((size_t)sup * H_ + h) * 4096 + i] = Pa[i >> 6][i & 63];
    Rsup[((size_t)sup * H_ + h) * 4096 + i] = Ra[i >> 6][i & 63];
  }
}

// ---------------- level B: exact fp32 scalar — unchanged ----------------
__global__ __launch_bounds__(256) void seq_levelB(const float* __restrict__ Psup,
    const float* __restrict__ Rsup, float* __restrict__ Msup) {
  __shared__ float Ms[64][65], Pi[64][65], Ri[64][65];
  const int h = blockIdx.x, tid = threadIdx.x;
  for (int i = tid; i < 4096; i += 256) Ms[i >> 6][i & 63] = 0.f;
  float pf[16], rf[16];
  {
    const float* ps = Psup + ((size_t)0 * H_ + h) * 4096;
    const float* rs = Rsup + ((size_t)0 * H_ + h) * 4096;
#pragma unroll
    for (int k = 0; k < 16; ++k) { int i = tid + k * 256; pf[k] = ps[i]; rf[k] = rs[i]; }
  }
  for (int s = 0; s < NSUP; ++s) {
#pragma unroll
    for (int k = 0; k < 16; ++k) {
      int i = tid + k * 256, r = i >> 6, cc = i & 63;
      Pi[r][cc] = pf[k];
      Ri[r][cc] = rf[k];
    }
    store64(Msup + ((size_t)s * H_ + h) * 4096, Ms, tid);
    __syncthreads();
    if (s + 1 < NSUP) {
      const float* ps = Psup + ((size_t)(s + 1) * H_ + h) * 4096;
      const float* rs = Rsup + ((size_t)(s + 1) * H_ + h) * 4096;
#pragma unroll
      for (int k = 0; k < 16; ++k) { int i = tid + k * 256; pf[k] = ps[i]; rf[k] = rs[i]; }
    }
    mm64(Ms, Pi, Ms, Ri, tid);
  }
}

// ---------------- level C (MFMA, bf16x3) — unchanged ----------------
template<typename PT>
__global__ __launch_bounds__(256) void seq_levelC(const PT* __restrict__ Pg,
    PT* __restrict__ Rg, const float* __restrict__ Msup) {
  __shared__ __align__(16) float Ms[64][68], Ri[64][68];
  __shared__ __align__(16) u16 Pih[64][72], Pil[64][72];
  const int sup = blockIdx.x, h = blockIdx.y, tid = threadIdx.x;
  const int w = tid >> 6, lane = tid & 63;
  const int fr = lane & 15, kq = lane >> 4, orow = kq * 4;
  const int xr = 16 * w + fr;

  auto upd = [&](float (*St)[68], const float (*Add)[68]) {
    short8 xh[2], xl[2];
#pragma unroll
    for (int s2 = 0; s2 < 2; ++s2) {
      const float* p = &St[xr][32 * s2 + 8 * kq];
#pragma unroll
      for (int j = 0; j < 8; ++j) {
        float v = p[j];
        u16 hb = f2bf(v);
        xh[s2][j] = (short)hb;
        xl[s2][j] = (short)f2bf(v - bf2f(hb));
      }
    }
    f32x4 acc[4];
#pragma unroll
    for (int ni = 0; ni < 4; ++ni) acc[ni] = (f32x4){0.f, 0.f, 0.f, 0.f};
#pragma unroll
    for (int ni = 0; ni < 4; ++ni)
#pragma unroll
      for (int s2 = 0; s2 < 2; ++s2) {
        short8 yh = *(const short8*)(&Pih[16 * ni + fr][32 * s2 + 8 * kq]);
        short8 yl = *(const short8*)(&Pil[16 * ni + fr][32 * s2 + 8 * kq]);
        acc[ni] = MFMA(xh[s2], yh, acc[ni], 0, 0, 0);
        acc[ni] = MFMA(xh[s2], yl, acc[ni], 0, 0, 0);
        acc[ni] = MFMA(xl[s2], yh, acc[ni], 0, 0, 0);
      }
#pragma unroll
    for (int ni = 0; ni < 4; ++ni)
#pragma unroll
      for (int rg = 0; rg < 4; ++rg) {
        float v = acc[ni][rg];
        if (Add) v += Add[16 * w + orow + rg][16 * ni + fr];
        St[16 * w + orow + rg][16 * ni + fr] = v;
      }
  };

  for (int i = tid; i < 4096; i += 256)
    Ms[i >> 6][i & 63] = Msup[((size_t)sup * H_ + h) * 4096 + i];
  float pf[16], rf[16];
  {
    const size_t slice = ((size_t)(sup * SUPW) * H_ + h) * 4096;
#pragma unroll
    for (int k = 0; k < 16; ++k) { int i = tid + k * 256; pf[k] = ldv(Pg[slice + i]); rf[k] = ldv(Rg[slice + i]); }
  }
  for (int s = 0; s < SUPW; ++s) {
    const size_t slice = ((size_t)(sup * SUPW + s) * H_ + h) * 4096;
#pragma unroll
    for (int k = 0; k < 16; ++k) {
      int i = tid + k * 256, d = i >> 6, cc = i & 63;
      float v = ((d == cc) ? 1.f : 0.f) - pf[k];
      u16 hb = f2bf(v);
      Pih[cc][d] = hb;
      Pil[cc][d] = f2bf(v - bf2f(hb));
      Ri[d][cc] = rf[k];
    }
    for (int i = tid; i < 4096; i += 256) stv(&Rg[slice + i], Ms[i >> 6][i & 63]);
    __syncthreads();
    if (s + 1 < SUPW) {
      const size_t sl2 = ((size_t)(sup * SUPW + s + 1) * H_ + h) * 4096;
#pragma unroll
      for (int k = 0; k < 16; ++k) { int i = tid + k * 256; pf[k] = ldv(Pg[sl2 + i]); rf[k] = ldv(Rg[sl2 + i]); }
    }
    upd(Ms, Ri);
    __syncthreads();
  }
}

// ---------------- phase 3: attn = E*M0^T + F — unchanged ----------------
template<typename PT>
__global__ __launch_bounds__(256) void phase3_kernel(
    const float* __restrict__ Eg, const u16* __restrict__ Fg,
    const PT* __restrict__ Mcg, u16* __restrict__ attn) {
  __shared__ float Es[64][65], Ms[64][65];
  const int c = blockIdx.x, h = blockIdx.y, tid = threadIdx.x;
  for (int i = tid; i < 4096; i += 256) {
    int r = i >> 6, d = i & 63, t = r >> 2, b = r & 3;
    size_t g = ((size_t)b * S_ + (size_t)c * CHUNK + t) * D_ + h * 64 + d;
    Es[r][d] = Eg[g];
    Ms[i >> 6][i & 63] = ldv(Mcg[((size_t)c * H_ + h) * 4096 + i]);
  }
  __syncthreads();
  const int r0 = (tid >> 4) * 4, d0 = (tid & 15) * 4;
  float a[4][4] = {};
  for (int k = 0; k < 64; ++k) {
    float ev[4], mv[4];
#pragma unroll
    for (int i = 0; i < 4; ++i) ev[i] = Es[r0 + i][k];
#pragma unroll
    for (int j = 0; j < 4; ++j) mv[j] = Ms[d0 + j][k];
#pragma unroll
    for (int i = 0; i < 4; ++i)
#pragma unroll
      for (int j = 0; j < 4; ++j) a[i][j] += ev[i] * mv[j];
  }
#pragma unroll
  for (int i = 0; i < 4; ++i)
#pragma unroll
    for (int j = 0; j < 4; ++j) {
      int r = r0 + i, d = d0 + j, t = r >> 2, b = r & 3;
      size_t g = ((size_t)b * S_ + (size_t)c * CHUNK + t) * D_ + h * 64 + d;
      attn[g] = f2bf(a[i][j] + bf2f(Fg[g]));
    }
}

// ---------------- launch ----------------
extern "C" void kernel_launch(void* const* d_in, const int* in_sizes, int n_in,
                              void* d_out, int out_size, void* d_ws, size_t ws_size,
                              hipStream_t stream) {
  (void)in_sizes; (void)n_in; (void)out_size;
  const float* x  = (const float*)d_in[0];
  const float* Wq = (const float*)d_in[1];
  const float* Wk = (const float*)d_in[2];
  const float* Wv = (const float*)d_in[3];
  const float* Wo = (const float*)d_in[4];
  float* out = (float*)d_out;

  char* w = (char*)d_ws;
  const size_t MB = 1024 * 1024;
  u16* Kbf = (u16*)w;
  u16* Vbf = (u16*)(w + 32 * MB);
  u16* xh  = (u16*)(w + 64 * MB);
  const bool big = ws_size >= 192 * MB;
  void* Preg = (void*)(w + 64 * MB);
  void* Rreg = big ? (void*)(w + 128 * MB) : (void*)(w + 96 * MB);
  float* Psup = (float*)w;
  float* Rsup = (float*)(w + 4 * MB);
  float* Msup = (float*)(w + 8 * MB);
  u16* attn = (u16*)Preg;
  u16* Wsp = (u16*)(w + 128 * MB);  // hi-only: q +0, k +1M, v +2M (u16); o reuses +0

  const size_t DSZ = (size_t)B_ * S_ * D_;  // 16777216
  cvt_hi_kernel<<<2048, 256, 0, stream>>>(x, xh, (int)(DSZ / 4));

  dim3 gg(128, 8);
  if (big) {
    cvt_hi3_kernel<<<dim3(512, 3), 256, 0, stream>>>(
        Wq, Wk, Wv, Wsp + 0 * 1048576u, Wsp + 1 * 1048576u, Wsp + 2 * 1048576u, 262144);
    gemm_axw<1, float><<<gg, 256, 0, stream>>>(xh, Wsp + 0 * 1048576u, out, 16384, 1024, 1024);
    gemm_axw<1, u16><<<gg, 256, 0, stream>>>(xh, Wsp + 1 * 1048576u, Kbf, 16384, 1024, 1024);
    gemm_axw<1, u16><<<gg, 256, 0, stream>>>(xh, Wsp + 2 * 1048576u, Vbf, 16384, 1024, 1024);
    float* P = (float*)Preg; float* R = (float*)Rreg;
    phase1_kernel<float><<<dim3(NCHUNK, H_), 256, 0, stream>>>(out, Kbf, Vbf, P, R);
    seq_levelA<float><<<dim3(NSUP, H_), 256, 0, stream>>>(P, R, Psup, Rsup);
    seq_levelB<<<dim3(H_), 256, 0, stream>>>(Psup, Rsup, Msup);
    seq_levelC<float><<<dim3(NSUP, H_), 256, 0, stream>>>(P, R, Msup);
    phase3_kernel<float><<<dim3(NCHUNK, H_), 256, 0, stream>>>(out, Vbf, R, attn);
    cvt_hi_kernel<<<512, 256, 0, stream>>>(Wo, Wsp + 0 * 1048576u, 262144);
    gemm_axw<1, float><<<gg, 256, 0, stream>>>(attn, Wsp + 0 * 1048576u, out, 16384, 1024, 1024);
  } else {
    gemm_axw<0, float><<<gg, 256, 0, stream>>>(xh, Wq, out, 16384, 1024, 1024);
    gemm_axw<0, u16><<<gg, 256, 0, stream>>>(xh, Wk, Kbf, 16384, 1024, 1024);
    gemm_axw<0, u16><<<gg, 256, 0, stream>>>(xh, Wv, Vbf, 16384, 1024, 1024);
    u16* P = (u16*)Preg; u16* R = (u16*)Rreg;
    phase1_kernel<u16><<<dim3(NCHUNK, H_), 256, 0, stream>>>(out, Kbf, Vbf, P, R);
    seq_levelA<u16><<<dim3(NSUP, H_), 256, 0, stream>>>(P, R, Psup, Rsup);
    seq_levelB<<<dim3(H_), 256, 0, stream>>>(Psup, Rsup, Msup);
    seq_levelC<u16><<<dim3(NSUP, H_), 256, 0, stream>>>(P, R, Msup);
    phase3_kernel<u16><<<dim3(NCHUNK, H_), 256, 0, stream>>>(out, Vbf, R, attn);
    gemm_axw<0, float><<<gg, 256, 0, stream>>>(attn, Wo, out, 16384, 1024, 1024);
  }
}

// Round 15
// 538.263 us; speedup vs baseline: 1.0849x; 1.0170x over previous
//
#include <hip/hip_runtime.h>

// L2RegressionAttention — chunked WY-transform.
// r15: P/R/Mc stored bf16 in the big path too (kernels already templated;
// cuts ~220MB HBM traffic). All 4 W converts front-loaded in one launch.
// Kernel bodies byte-identical to r14 (GEMM=r12 optimum, phase1 r14).
// B=4, S=4096, D=1024, H=16, hd=64, eta = 0.1/4 = 0.025.

typedef unsigned short u16;
typedef __attribute__((ext_vector_type(8))) short short8;
typedef __attribute__((ext_vector_type(4))) float f32x4;

#define B_ 4
#define S_ 4096
#define D_ 1024
#define H_ 16
#define CHUNK 16
#define NCHUNK 256
#define SUPW 16
#define NSUP 16
#define ETA 0.025f

__device__ __forceinline__ u16 f2bf(float f) {
  unsigned u = __builtin_bit_cast(unsigned, f);
  u += 0x7fffu + ((u >> 16) & 1u);
  return (u16)(u >> 16);
}
__device__ __forceinline__ float bf2f(u16 s) {
  unsigned u = ((unsigned)s) << 16;
  return __builtin_bit_cast(float, u);
}
__device__ __forceinline__ float ldv(float v) { return v; }
__device__ __forceinline__ float ldv(u16 v) { return bf2f(v); }
__device__ __forceinline__ void stv(float* p, float v) { *p = v; }
__device__ __forceinline__ void stv(u16* p, float v) { *p = f2bf(v); }

#define MFMA __builtin_amdgcn_mfma_f32_16x16x32_bf16

__device__ __forceinline__ void gload16(const void* g, void* l) {
  __builtin_amdgcn_global_load_lds(
      (__attribute__((address_space(1))) void*)g,
      (__attribute__((address_space(3))) void*)l, 16, 0, 0);
}

// ---------------- fp32 -> bf16 hi-only convert ----------------
__global__ void cvt_hi_kernel(const float* __restrict__ x, u16* __restrict__ hi, int n4) {
  int i = blockIdx.x * blockDim.x + threadIdx.x;
  int stride = gridDim.x * blockDim.x;
  for (; i < n4; i += stride) {
    float4 v = ((const float4*)x)[i];
    ushort4 h;
    h.x = f2bf(v.x); h.y = f2bf(v.y); h.z = f2bf(v.z); h.w = f2bf(v.w);
    ((ushort4*)hi)[i] = h;
  }
}

// four weight matrices in one launch (blockIdx.y selects)
__global__ void cvt_hi4_kernel(const float* __restrict__ a, const float* __restrict__ b,
                               const float* __restrict__ c, const float* __restrict__ d,
                               u16* __restrict__ o, int n4) {
  const float* src = (blockIdx.y == 0) ? a : (blockIdx.y == 1) ? b
                   : (blockIdx.y == 2) ? c : d;
  u16* dst = o + (size_t)blockIdx.y * 1048576u;
  int i = blockIdx.x * blockDim.x + threadIdx.x;
  int stride = gridDim.x * blockDim.x;
  for (; i < n4; i += stride) {
    float4 v = ((const float4*)src)[i];
    ushort4 h;
    h.x = f2bf(v.x); h.y = f2bf(v.y); h.z = f2bf(v.z); h.w = f2bf(v.w);
    ((ushort4*)dst)[i] = h;
  }
}

// ---------------- GEMM: C[M][N] = A * B^T (r12 optimum) ----------------
template<int BPRE, typename OutT>
__global__ __launch_bounds__(256) void gemm_axw(
    const u16* __restrict__ Ahg, const void* __restrict__ Bhp,
    OutT* __restrict__ C, int M, int N, int K) {
  __shared__ __align__(16) u16 Ahs[2][128][32];
  __shared__ __align__(16) u16 Bhs[2][128][32];
  const int tid = threadIdx.x, w = tid >> 6, lane = tid & 63;
  const int bm = blockIdx.x * 128, bn = blockIdx.y * 128;
  const int wm = (w >> 1) * 64, wn = (w & 1) * 64;
  const int fr = lane & 15, kb = lane >> 4;
  const int lrow = lane >> 2, lcol = (lane & 3) * 8;

  auto stage = [&](int buf, int k0) {
    {
      const size_t rb = (size_t)(bm + w * 32 + lrow) * K + k0 + lcol;
      gload16(Ahg + rb, &Ahs[buf][w * 32][0]);
      gload16(Ahg + rb + (size_t)16 * K, &Ahs[buf][w * 32 + 16][0]);
    }
    if constexpr (BPRE) {
      const u16* Bhg = (const u16*)Bhp;
      const size_t rb = (size_t)(bn + w * 32 + lrow) * K + k0 + lcol;
      gload16(Bhg + rb, &Bhs[buf][w * 32][0]);
      gload16(Bhg + rb + (size_t)16 * K, &Bhs[buf][w * 32 + 16][0]);
    } else {
      const float* Bm = (const float*)Bhp;
#pragma unroll
      for (int i2 = 0; i2 < 4; ++i2) {
        int e = tid + i2 * 256, r = e >> 3, sg = (e & 7) * 4;
        float4 v = *(const float4*)(&Bm[(size_t)(bn + r) * K + k0 + sg]);
        ushort4 hq;
        hq.x = f2bf(v.x); hq.y = f2bf(v.y); hq.z = f2bf(v.z); hq.w = f2bf(v.w);
        *(ushort4*)(&Bhs[buf][r][sg]) = hq;
      }
    }
  };
  auto compute = [&](int buf, f32x4 (*acc)[4]) {
    short8 ah[4], bh[4];
#pragma unroll
    for (int mi = 0; mi < 4; ++mi)
      ah[mi] = *(const short8*)(&Ahs[buf][wm + mi * 16 + fr][kb * 8]);
#pragma unroll
    for (int ni = 0; ni < 4; ++ni)
      bh[ni] = *(const short8*)(&Bhs[buf][wn + ni * 16 + fr][kb * 8]);
#pragma unroll
    for (int mi = 0; mi < 4; ++mi)
#pragma unroll
      for (int ni = 0; ni < 4; ++ni)
        acc[mi][ni] = MFMA(ah[mi], bh[ni], acc[mi][ni], 0, 0, 0);
  };

  f32x4 acc[4][4];
#pragma unroll
  for (int i = 0; i < 4; ++i)
#pragma unroll
    for (int j = 0; j < 4; ++j) acc[i][j] = (f32x4){0.f, 0.f, 0.f, 0.f};

  const int nt = K >> 5;
  stage(0, 0);
  asm volatile("s_waitcnt vmcnt(0)" ::: "memory");
  __syncthreads();
  int cur = 0;
  for (int t = 0; t < nt; ++t) {
    if (t + 1 < nt) stage(cur ^ 1, (t + 1) * 32);
    compute(cur, acc);
    asm volatile("s_waitcnt vmcnt(0)" ::: "memory");
    __syncthreads();
    cur ^= 1;
  }
  const int fc = lane & 15, fr4 = (lane >> 4) * 4;
#pragma unroll
  for (int mi = 0; mi < 4; ++mi)
#pragma unroll
    for (int ni = 0; ni < 4; ++ni) {
      int gm = bm + wm + mi * 16 + fr4;
      int gn = bn + wn + ni * 16 + fc;
#pragma unroll
      for (int rg = 0; rg < 4; ++rg)
        stv(&C[(size_t)(gm + rg) * N + gn], acc[mi][ni][rg]);
    }
}

// ---------------- phase 1 (MFMA, pre-masked N, fused U/W, 1-pass sq1) ----------------
template<typename PT>
__global__ __launch_bounds__(256) void phase1_kernel(
    float* __restrict__ Qg, const u16* __restrict__ Kg, u16* __restrict__ Vg,
    PT* __restrict__ Pg, PT* __restrict__ Rg) {
  __shared__ __align__(16) u16 Ks[64][72];
  __shared__ __align__(16) u16 KsT[64][72];
  __shared__ __align__(16) u16 Gh[64][72];
  __shared__ __align__(16) u16 Gl[64][72];
  __shared__ __align__(16) float Ut[64][68];
  __shared__ __align__(16) float Wt[64][68];

  const int c = blockIdx.x, h = blockIdx.y, tid = threadIdx.x;
  const int w = tid >> 6, lane = tid & 63;
  const int fr = lane & 15, kq = lane >> 4, orow = kq * 4;
  const int xr = 16 * w + fr;

  auto gidx = [&](int r, int d) -> size_t {
    return ((size_t)(r & 3) * S_ + (size_t)c * CHUNK + (r >> 2)) * D_ + h * 64 + d;
  };
  auto ldb = [&](const u16 (*M)[72], int row, int s) -> short8 {
    return *(const short8*)(&M[row][32 * s + 8 * kq]);
  };
  auto ldf = [&](const float (*M)[68], int row, int s, short8& hh, short8& ll) {
    const float* p = &M[row][32 * s + 8 * kq];
#pragma unroll
    for (int j = 0; j < 8; ++j) {
      float v = p[j];
      u16 hb = f2bf(v);
      hh[j] = (short)hb;
      ll[j] = (short)f2bf(v - bf2f(hb));
    }
  };
  auto ldfh = [&](const float (*M)[68], int row, int s) -> short8 {
    const float* p = &M[row][32 * s + 8 * kq];
    short8 hh;
#pragma unroll
    for (int j = 0; j < 8; ++j) hh[j] = (short)f2bf(p[j]);
    return hh;
  };

  for (int i = tid; i < 4096; i += 256) {
    int r = i >> 6, d = i & 63;
    size_t g = gidx(r, d);
    u16 kraw = Kg[g];
    Ks[r][d] = kraw;
    KsT[d][r] = kraw;
    Wt[d][r] = ETA * bf2f(kraw);
    Ut[d][r] = ETA * bf2f(Vg[g]);
  }
  __syncthreads();  // (1)

  f32x4 gacc[4];
#pragma unroll
  for (int ni = 0; ni < 4; ++ni) gacc[ni] = (f32x4){0.f, 0.f, 0.f, 0.f};
  {
    short8 xf[2];
#pragma unroll
    for (int s = 0; s < 2; ++s) xf[s] = ldb(Ks, xr, s);
#pragma unroll
    for (int ni = 0; ni < 4; ++ni)
#pragma unroll
      for (int s = 0; s < 2; ++s)
        gacc[ni] = MFMA(xf[s], ldb(Ks, 16 * ni + fr, s), gacc[ni], 0, 0, 0);
  }

  float sreg[4][4];
  {
    short8 xh[2], xl[2];
#pragma unroll
    for (int s = 0; s < 2; ++s) {
      const float* qp = &Qg[gidx(xr, 32 * s + 8 * kq)];
#pragma unroll
      for (int j = 0; j < 8; ++j) {
        float v = qp[j];
        u16 hb = f2bf(v);
        xh[s][j] = (short)hb;
        xl[s][j] = (short)f2bf(v - bf2f(hb));
      }
    }
    f32x4 acc[4];
#pragma unroll
    for (int ni = 0; ni < 4; ++ni) acc[ni] = (f32x4){0.f, 0.f, 0.f, 0.f};
#pragma unroll
    for (int ni = 0; ni < 4; ++ni)
#pragma unroll
      for (int s = 0; s < 2; ++s) {
        short8 yf = ldb(Ks, 16 * ni + fr, s);
        acc[ni] = MFMA(xh[s], yf, acc[ni], 0, 0, 0);
        acc[ni] = MFMA(xl[s], yf, acc[ni], 0, 0, 0);
      }
#pragma unroll
    for (int ni = 0; ni < 4; ++ni)
#pragma unroll
      for (int rg = 0; rg < 4; ++rg) {
        int r = 16 * w + orow + rg, cc = 16 * ni + fr;
        sreg[ni][rg] = ((r >> 2) >= (cc >> 2)) ? acc[ni][rg] : 0.f;
      }
  }
  __syncthreads();  // (1b)

#pragma unroll
  for (int ni = 0; ni < 4; ++ni)
#pragma unroll
    for (int rg = 0; rg < 4; ++rg) {
      float v = -ETA * gacc[ni][rg];
      u16 hb = f2bf(v);
      u16 lb = f2bf(v - bf2f(hb));
      int rr = 16 * w + orow + rg, cc = 16 * ni + fr;
      bool low = (rr >> 2) > (cc >> 2);
      u16 hm = low ? hb : (u16)0, lm = low ? lb : (u16)0;
      Gh[rr][cc] = hm;
      Gl[rr][cc] = lm;
      Ks[cc][rr] = hm;   // NU-h (symmetry)
    }
  __syncthreads();  // (2)

  {
    short8 uh[2], ul[2], wh[2], wl[2];
#pragma unroll
    for (int s = 0; s < 2; ++s) { ldf(Ut, xr, s, uh[s], ul[s]); ldf(Wt, xr, s, wh[s], wl[s]); }
    f32x4 aU[4], aW[4];
#pragma unroll
    for (int ni = 0; ni < 4; ++ni) { aU[ni] = (f32x4){0.f,0.f,0.f,0.f}; aW[ni] = (f32x4){0.f,0.f,0.f,0.f}; }
#pragma unroll
    for (int ni = 0; ni < 4; ++ni)
#pragma unroll
      for (int s = 0; s < 2; ++s) {
        short8 yh = ldb(Gh, 16 * ni + fr, s);
        short8 yl = ldb(Gl, 16 * ni + fr, s);
        aU[ni] = MFMA(uh[s], yh, aU[ni], 0, 0, 0);
        aU[ni] = MFMA(uh[s], yl, aU[ni], 0, 0, 0);
        aU[ni] = MFMA(ul[s], yh, aU[ni], 0, 0, 0);
        aW[ni] = MFMA(wh[s], yh, aW[ni], 0, 0, 0);
        aW[ni] = MFMA(wh[s], yl, aW[ni], 0, 0, 0);
        aW[ni] = MFMA(wl[s], yh, aW[ni], 0, 0, 0);
      }
#pragma unroll
    for (int ni = 0; ni < 4; ++ni)
#pragma unroll
      for (int rg = 0; rg < 4; ++rg) {
        Ut[16 * w + orow + rg][16 * ni + fr] += aU[ni][rg];
        Wt[16 * w + orow + rg][16 * ni + fr] += aW[ni][rg];
      }
  }
  auto appSf = [&](const u16 (*Np)[72]) {
    short8 xu[2], xw[2];
#pragma unroll
    for (int s = 0; s < 2; ++s) { xu[s] = ldfh(Ut, xr, s); xw[s] = ldfh(Wt, xr, s); }
    f32x4 aU[4], aW[4];
#pragma unroll
    for (int ni = 0; ni < 4; ++ni) { aU[ni] = (f32x4){0.f,0.f,0.f,0.f}; aW[ni] = (f32x4){0.f,0.f,0.f,0.f}; }
#pragma unroll
    for (int ni = 0; ni < 4; ++ni)
#pragma unroll
      for (int s = 0; s < 2; ++s) {
        short8 yf = ldb(Np, 16 * ni + fr, s);
        aU[ni] = MFMA(xu[s], yf, aU[ni], 0, 0, 0);
        aW[ni] = MFMA(xw[s], yf, aW[ni], 0, 0, 0);
      }
#pragma unroll
    for (int ni = 0; ni < 4; ++ni)
#pragma unroll
      for (int rg = 0; rg < 4; ++rg) {
        Ut[16 * w + orow + rg][16 * ni + fr] += aU[ni][rg];
        Wt[16 * w + orow + rg][16 * ni + fr] += aW[ni][rg];
      }
  };

  {
    f32x4 sq[4];
#pragma unroll
    for (int ni = 0; ni < 4; ++ni) sq[ni] = (f32x4){0.f, 0.f, 0.f, 0.f};
    short8 xh[2];
#pragma unroll
    for (int s = 0; s < 2; ++s) xh[s] = ldb(Gh, xr, s);
#pragma unroll
    for (int ni = 0; ni < 4; ++ni)
#pragma unroll
      for (int s = 0; s < 2; ++s)
        sq[ni] = MFMA(xh[s], ldb(Ks, 16 * ni + fr, s), sq[ni], 0, 0, 0);
    __syncthreads();  // (3)
#pragma unroll
    for (int ni = 0; ni < 4; ++ni)
#pragma unroll
      for (int rg = 0; rg < 4; ++rg) {
        u16 b = f2bf(sq[ni][rg]);
        int rr = 16 * w + orow + rg, cc = 16 * ni + fr;
        Ks[rr][cc] = b;   // N^2
        Gh[cc][rr] = b;   // N^2T
      }
  }
  __syncthreads();  // (4)

  appSf(Ks);
  {
    f32x4 sq[4];
#pragma unroll
    for (int ni = 0; ni < 4; ++ni) sq[ni] = (f32x4){0.f, 0.f, 0.f, 0.f};
    short8 xf[2];
#pragma unroll
    for (int s = 0; s < 2; ++s) xf[s] = ldb(Ks, xr, s);
#pragma unroll
    for (int ni = 0; ni < 4; ++ni)
#pragma unroll
      for (int s = 0; s < 2; ++s)
        sq[ni] = MFMA(xf[s], ldb(Gh, 16 * ni + fr, s), sq[ni], 0, 0, 0);
    __syncthreads();  // (5)
#pragma unroll
    for (int ni = 0; ni < 4; ++ni)
#pragma unroll
      for (int rg = 0; rg < 4; ++rg) {
        u16 b = f2bf(sq[ni][rg]);
        int rr = 16 * w + orow + rg, cc = 16 * ni + fr;
        Gl[rr][cc] = b;   // N^4
        Ks[cc][rr] = b;   // N^4T
      }
  }
  __syncthreads();  // (6)

  appSf(Gl);
  {
    f32x4 sq[4];
#pragma unroll
    for (int ni = 0; ni < 4; ++ni) sq[ni] = (f32x4){0.f, 0.f, 0.f, 0.f};
    short8 xf[2];
#pragma unroll
    for (int s = 0; s < 2; ++s) xf[s] = ldb(Gl, xr, s);
#pragma unroll
    for (int ni = 0; ni < 4; ++ni)
#pragma unroll
      for (int s = 0; s < 2; ++s)
        sq[ni] = MFMA(xf[s], ldb(Ks, 16 * ni + fr, s), sq[ni], 0, 0, 0);
#pragma unroll
    for (int ni = 0; ni < 4; ++ni)
#pragma unroll
      for (int rg = 0; rg < 4; ++rg)
        Gh[16 * w + orow + rg][16 * ni + fr] = f2bf(sq[ni][rg]);  // N^8
  }
  __syncthreads();  // (7)

  appSf(Gh);
  __syncthreads();  // (7b)

  const size_t base = ((size_t)c * H_ + h) * 4096;
  {
    short8 wh[2], wl[2], uh[2], ul[2];
#pragma unroll
    for (int s = 0; s < 2; ++s) { ldf(Wt, xr, s, wh[s], wl[s]); ldf(Ut, xr, s, uh[s], ul[s]); }
    f32x4 aP[4], aR[4];
#pragma unroll
    for (int ni = 0; ni < 4; ++ni) { aP[ni] = (f32x4){0.f,0.f,0.f,0.f}; aR[ni] = (f32x4){0.f,0.f,0.f,0.f}; }
#pragma unroll
    for (int ni = 0; ni < 4; ++ni)
#pragma unroll
      for (int s = 0; s < 2; ++s) {
        short8 yf = ldb(KsT, 16 * ni + fr, s);
        aP[ni] = MFMA(wh[s], yf, aP[ni], 0, 0, 0);
        aP[ni] = MFMA(wl[s], yf, aP[ni], 0, 0, 0);
        aR[ni] = MFMA(uh[s], yf, aR[ni], 0, 0, 0);
        aR[ni] = MFMA(ul[s], yf, aR[ni], 0, 0, 0);
      }
#pragma unroll
    for (int ni = 0; ni < 4; ++ni)
#pragma unroll
      for (int rg = 0; rg < 4; ++rg) {
        stv(&Pg[base + (16 * w + orow + rg) * 64 + 16 * ni + fr], aP[ni][rg]);
        stv(&Rg[base + (16 * w + orow + rg) * 64 + 16 * ni + fr], aR[ni][rg]);
      }
  }
  {
    const int r = tid >> 2, d0 = (tid & 3) * 16;
    short8 v0, v1;
#pragma unroll
    for (int j = 0; j < 8; ++j) v0[j] = (short)f2bf(Wt[r][d0 + j]);
#pragma unroll
    for (int j = 0; j < 8; ++j) v1[j] = (short)f2bf(Wt[r][d0 + 8 + j]);
    *(short8*)(&Gh[r][d0]) = v0;
    *(short8*)(&Gh[r][d0 + 8]) = v1;
#pragma unroll
    for (int j = 0; j < 8; ++j) v0[j] = (short)f2bf(Ut[r][d0 + j]);
#pragma unroll
    for (int j = 0; j < 8; ++j) v1[j] = (short)f2bf(Ut[r][d0 + 8 + j]);
    *(short8*)(&Gl[r][d0]) = v0;
    *(short8*)(&Gl[r][d0 + 8]) = v1;
  }
#pragma unroll
  for (int ni = 0; ni < 4; ++ni)
#pragma unroll
    for (int rg = 0; rg < 4; ++rg)
      Ks[16 * w + orow + rg][16 * ni + fr] = f2bf(sreg[ni][rg]);  // Sm
  __syncthreads();  // (8)

  {
    short8 xs[2];
#pragma unroll
    for (int s = 0; s < 2; ++s) xs[s] = ldb(Ks, xr, s);
    f32x4 accE[4], accF[4];
#pragma unroll
    for (int ni = 0; ni < 4; ++ni) {
      accE[ni] = (f32x4){0.f, 0.f, 0.f, 0.f};
      accF[ni] = (f32x4){0.f, 0.f, 0.f, 0.f};
    }
#pragma unroll
    for (int ni = 0; ni < 4; ++ni)
#pragma unroll
      for (int s = 0; s < 2; ++s) {
        accE[ni] = MFMA(xs[s], ldb(Gh, 16 * ni + fr, s), accE[ni], 0, 0, 0);
        accF[ni] = MFMA(xs[s], ldb(Gl, 16 * ni + fr, s), accF[ni], 0, 0, 0);
      }
#pragma unroll
    for (int ni = 0; ni < 4; ++ni)
#pragma unroll
      for (int rg = 0; rg < 4; ++rg) {
        int r = 16 * w + orow + rg, d = 16 * ni + fr;
        size_t g = gidx(r, d);
        float qv = Qg[g];
        Qg[g] = qv - accE[ni][rg];
        Vg[g] = f2bf(accF[ni][rg]);
      }
  }
}

// ---------------- scalar 64x64 helpers (levelB only) ----------------
__device__ __forceinline__ void store64(float* dst, const float (*src)[65], int tid) {
  for (int i = tid; i < 4096; i += 256) dst[i] = src[i >> 6][i & 63];
}
__device__ __forceinline__ void mm64(const float (*X)[65], const float (*Y)[65],
                                     float (*Dst)[65], const float (*Add)[65], int tid) {
  const int r0 = (tid >> 4) * 4, c0 = (tid & 15) * 4;
  float a[4][4] = {};
  for (int d = 0; d < 64; ++d) {
    float xv[4], yv[4];
#pragma unroll
    for (int i = 0; i < 4; ++i) xv[i] = X[r0 + i][d];
#pragma unroll
    for (int j = 0; j < 4; ++j) yv[j] = Y[d][c0 + j];
#pragma unroll
    for (int i = 0; i < 4; ++i)
#pragma unroll
      for (int j = 0; j < 4; ++j) a[i][j] += xv[i] * yv[j];
  }
  __syncthreads();
#pragma unroll
  for (int i = 0; i < 4; ++i)
#pragma unroll
    for (int j = 0; j < 4; ++j) {
      float v = a[i][j];
      if (Add) v += Add[r0 + i][c0 + j];
      Dst[r0 + i][c0 + j] = v;
    }
  __syncthreads();
}

// ---------------- level A (MFMA, bf16x3) — unchanged ----------------
template<typename PT>
__global__ __launch_bounds__(256) void seq_levelA(const PT* __restrict__ Pg,
    const PT* __restrict__ Rg, float* __restrict__ Psup, float* __restrict__ Rsup) {
  __shared__ __align__(16) float Pa[64][68], Ra[64][68], Ri[64][68];
  __shared__ __align__(16) u16 Pih[64][72], Pil[64][72];
  const int sup = blockIdx.x, h = blockIdx.y, tid = threadIdx.x;
  const int w = tid >> 6, lane = tid & 63;
  const int fr = lane & 15, kq = lane >> 4, orow = kq * 4;
  const int xr = 16 * w + fr;
  const int cbase = sup * SUPW;

  auto upd = [&](float (*St)[68], const float (*Add)[68]) {
    short8 xh[2], xl[2];
#pragma unroll
    for (int s2 = 0; s2 < 2; ++s2) {
      const float* p = &St[xr][32 * s2 + 8 * kq];
#pragma unroll
      for (int j = 0; j < 8; ++j) {
        float v = p[j];
        u16 hb = f2bf(v);
        xh[s2][j] = (short)hb;
        xl[s2][j] = (short)f2bf(v - bf2f(hb));
      }
    }
    f32x4 acc[4];
#pragma unroll
    for (int ni = 0; ni < 4; ++ni) acc[ni] = (f32x4){0.f, 0.f, 0.f, 0.f};
#pragma unroll
    for (int ni = 0; ni < 4; ++ni)
#pragma unroll
      for (int s2 = 0; s2 < 2; ++s2) {
        short8 yh = *(const short8*)(&Pih[16 * ni + fr][32 * s2 + 8 * kq]);
        short8 yl = *(const short8*)(&Pil[16 * ni + fr][32 * s2 + 8 * kq]);
        acc[ni] = MFMA(xh[s2], yh, acc[ni], 0, 0, 0);
        acc[ni] = MFMA(xh[s2], yl, acc[ni], 0, 0, 0);
        acc[ni] = MFMA(xl[s2], yh, acc[ni], 0, 0, 0);
      }
#pragma unroll
    for (int ni = 0; ni < 4; ++ni)
#pragma unroll
      for (int rg = 0; rg < 4; ++rg) {
        float v = acc[ni][rg];
        if (Add) v += Add[16 * w + orow + rg][16 * ni + fr];
        St[16 * w + orow + rg][16 * ni + fr] = v;
      }
  };

  {
    const PT* ps = Pg + ((size_t)cbase * H_ + h) * 4096;
    const PT* rs = Rg + ((size_t)cbase * H_ + h) * 4096;
    for (int i = tid; i < 4096; i += 256) {
      int r = i >> 6, cc = i & 63;
      Pa[r][cc] = ((r == cc) ? 1.f : 0.f) - ldv(ps[i]);
      Ra[r][cc] = ldv(rs[i]);
    }
  }
  float pf[16], rf[16];
  {
    const PT* ps = Pg + ((size_t)(cbase + 1) * H_ + h) * 4096;
    const PT* rs = Rg + ((size_t)(cbase + 1) * H_ + h) * 4096;
#pragma unroll
    for (int k = 0; k < 16; ++k) { int i = tid + k * 256; pf[k] = ldv(ps[i]); rf[k] = ldv(rs[i]); }
  }
  for (int s = 1; s < SUPW; ++s) {
#pragma unroll
    for (int k = 0; k < 16; ++k) {
      int i = tid + k * 256, d = i >> 6, cc = i & 63;
      float v = ((d == cc) ? 1.f : 0.f) - pf[k];
      u16 hb = f2bf(v);
      Pih[cc][d] = hb;
      Pil[cc][d] = f2bf(v - bf2f(hb));
      Ri[d][cc] = rf[k];
    }
    __syncthreads();
    if (s + 1 < SUPW) {
      const PT* ps = Pg + ((size_t)(cbase + s + 1) * H_ + h) * 4096;
      const PT* rs = Rg + ((size_t)(cbase + s + 1) * H_ + h) * 4096;
#pragma unroll
      for (int k = 0; k < 16; ++k) { int i = tid + k * 256; pf[k] = ldv(ps[i]); rf[k] = ldv(rs[i]); }
    }
    upd(Pa, nullptr);
    upd(Ra, Ri);
    __syncthreads();
  }
  for (int i = tid; i < 4096; i += 256) {
    Psup[((size_t)sup * H_ + h) * 4096 + i] = Pa[i >> 6][i & 63];
    Rsup[((size_t)sup * H_ + h) * 4096 + i] = Ra[i >> 6][i & 63];
  }
}

// ---------------- level B: exact fp32 scalar — unchanged ----------------
__global__ __launch_bounds__(256) void seq_levelB(const float* __restrict__ Psup,
    const float* __restrict__ Rsup, float* __restrict__ Msup) {
  __shared__ float Ms[64][65], Pi[64][65], Ri[64][65];
  const int h = blockIdx.x, tid = threadIdx.x;
  for (int i = tid; i < 4096; i += 256) Ms[i >> 6][i & 63] = 0.f;
  float pf[16], rf[16];
  {
    const float* ps = Psup + ((size_t)0 * H_ + h) * 4096;
    const float* rs = Rsup + ((size_t)0 * H_ + h) * 4096;
#pragma unroll
    for (int k = 0; k < 16; ++k) { int i = tid + k * 256; pf[k] = ps[i]; rf[k] = rs[i]; }
  }
  for (int s = 0; s < NSUP; ++s) {
#pragma unroll
    for (int k = 0; k < 16; ++k) {
      int i = tid + k * 256, r = i >> 6, cc = i & 63;
      Pi[r][cc] = pf[k];
      Ri[r][cc] = rf[k];
    }
    store64(Msup + ((size_t)s * H_ + h) * 4096, Ms, tid);
    __syncthreads();
    if (s + 1 < NSUP) {
      const float* ps = Psup + ((size_t)(s + 1) * H_ + h) * 4096;
      const float* rs = Rsup + ((size_t)(s + 1) * H_ + h) * 4096;
#pragma unroll
      for (int k = 0; k < 16; ++k) { int i = tid + k * 256; pf[k] = ps[i]; rf[k] = rs[i]; }
    }
    mm64(Ms, Pi, Ms, Ri, tid);
  }
}

// ---------------- level C (MFMA, bf16x3) — unchanged ----------------
template<typename PT>
__global__ __launch_bounds__(256) void seq_levelC(const PT* __restrict__ Pg,
    PT* __restrict__ Rg, const float* __restrict__ Msup) {
  __shared__ __align__(16) float Ms[64][68], Ri[64][68];
  __shared__ __align__(16) u16 Pih[64][72], Pil[64][72];
  const int sup = blockIdx.x, h = blockIdx.y, tid = threadIdx.x;
  const int w = tid >> 6, lane = tid & 63;
  const int fr = lane & 15, kq = lane >> 4, orow = kq * 4;
  const int xr = 16 * w + fr;

  auto upd = [&](float (*St)[68], const float (*Add)[68]) {
    short8 xh[2], xl[2];
#pragma unroll
    for (int s2 = 0; s2 < 2; ++s2) {
      const float* p = &St[xr][32 * s2 + 8 * kq];
#pragma unroll
      for (int j = 0; j < 8; ++j) {
        float v = p[j];
        u16 hb = f2bf(v);
        xh[s2][j] = (short)hb;
        xl[s2][j] = (short)f2bf(v - bf2f(hb));
      }
    }
    f32x4 acc[4];
#pragma unroll
    for (int ni = 0; ni < 4; ++ni) acc[ni] = (f32x4){0.f, 0.f, 0.f, 0.f};
#pragma unroll
    for (int ni = 0; ni < 4; ++ni)
#pragma unroll
      for (int s2 = 0; s2 < 2; ++s2) {
        short8 yh = *(const short8*)(&Pih[16 * ni + fr][32 * s2 + 8 * kq]);
        short8 yl = *(const short8*)(&Pil[16 * ni + fr][32 * s2 + 8 * kq]);
        acc[ni] = MFMA(xh[s2], yh, acc[ni], 0, 0, 0);
        acc[ni] = MFMA(xh[s2], yl, acc[ni], 0, 0, 0);
        acc[ni] = MFMA(xl[s2], yh, acc[ni], 0, 0, 0);
      }
#pragma unroll
    for (int ni = 0; ni < 4; ++ni)
#pragma unroll
      for (int rg = 0; rg < 4; ++rg) {
        float v = acc[ni][rg];
        if (Add) v += Add[16 * w + orow + rg][16 * ni + fr];
        St[16 * w + orow + rg][16 * ni + fr] = v;
      }
  };

  for (int i = tid; i < 4096; i += 256)
    Ms[i >> 6][i & 63] = Msup[((size_t)sup * H_ + h) * 4096 + i];
  float pf[16], rf[16];
  {
    const size_t slice = ((size_t)(sup * SUPW) * H_ + h) * 4096;
#pragma unroll
    for (int k = 0; k < 16; ++k) { int i = tid + k * 256; pf[k] = ldv(Pg[slice + i]); rf[k] = ldv(Rg[slice + i]); }
  }
  for (int s = 0; s < SUPW; ++s) {
    const size_t slice = ((size_t)(sup * SUPW + s) * H_ + h) * 4096;
#pragma unroll
    for (int k = 0; k < 16; ++k) {
      int i = tid + k * 256, d = i >> 6, cc = i & 63;
      float v = ((d == cc) ? 1.f : 0.f) - pf[k];
      u16 hb = f2bf(v);
      Pih[cc][d] = hb;
      Pil[cc][d] = f2bf(v - bf2f(hb));
      Ri[d][cc] = rf[k];
    }
    for (int i = tid; i < 4096; i += 256) stv(&Rg[slice + i], Ms[i >> 6][i & 63]);
    __syncthreads();
    if (s + 1 < SUPW) {
      const size_t sl2 = ((size_t)(sup * SUPW + s + 1) * H_ + h) * 4096;
#pragma unroll
      for (int k = 0; k < 16; ++k) { int i = tid + k * 256; pf[k] = ldv(Pg[sl2 + i]); rf[k] = ldv(Rg[sl2 + i]); }
    }
    upd(Ms, Ri);
    __syncthreads();
  }
}

// ---------------- phase 3: attn = E*M0^T + F — unchanged ----------------
template<typename PT>
__global__ __launch_bounds__(256) void phase3_kernel(
    const float* __restrict__ Eg, const u16* __restrict__ Fg,
    const PT* __restrict__ Mcg, u16* __restrict__ attn) {
  __shared__ float Es[64][65], Ms[64][65];
  const int c = blockIdx.x, h = blockIdx.y, tid = threadIdx.x;
  for (int i = tid; i < 4096; i += 256) {
    int r = i >> 6, d = i & 63, t = r >> 2, b = r & 3;
    size_t g = ((size_t)b * S_ + (size_t)c * CHUNK + t) * D_ + h * 64 + d;
    Es[r][d] = Eg[g];
    Ms[i >> 6][i & 63] = ldv(Mcg[((size_t)c * H_ + h) * 4096 + i]);
  }
  __syncthreads();
  const int r0 = (tid >> 4) * 4, d0 = (tid & 15) * 4;
  float a[4][4] = {};
  for (int k = 0; k < 64; ++k) {
    float ev[4], mv[4];
#pragma unroll
    for (int i = 0; i < 4; ++i) ev[i] = Es[r0 + i][k];
#pragma unroll
    for (int j = 0; j < 4; ++j) mv[j] = Ms[d0 + j][k];
#pragma unroll
    for (int i = 0; i < 4; ++i)
#pragma unroll
      for (int j = 0; j < 4; ++j) a[i][j] += ev[i] * mv[j];
  }
#pragma unroll
  for (int i = 0; i < 4; ++i)
#pragma unroll
    for (int j = 0; j < 4; ++j) {
      int r = r0 + i, d = d0 + j, t = r >> 2, b = r & 3;
      size_t g = ((size_t)b * S_ + (size_t)c * CHUNK + t) * D_ + h * 64 + d;
      attn[g] = f2bf(a[i][j] + bf2f(Fg[g]));
    }
}

// ---------------- launch ----------------
extern "C" void kernel_launch(void* const* d_in, const int* in_sizes, int n_in,
                              void* d_out, int out_size, void* d_ws, size_t ws_size,
                              hipStream_t stream) {
  (void)in_sizes; (void)n_in; (void)out_size;
  const float* x  = (const float*)d_in[0];
  const float* Wq = (const float*)d_in[1];
  const float* Wk = (const float*)d_in[2];
  const float* Wv = (const float*)d_in[3];
  const float* Wo = (const float*)d_in[4];
  float* out = (float*)d_out;

  char* w = (char*)d_ws;
  const size_t MB = 1024 * 1024;
  // [0,32) Kbf -> smalls ; [32,64) Vbf -> F ; [64,96) xh -> P bf16 -> attn ;
  // [96,128) R bf16 -> Mc ; [128,136) Wsp (4x 1M u16: q,k,v,o)
  u16* Kbf = (u16*)w;
  u16* Vbf = (u16*)(w + 32 * MB);
  u16* xh  = (u16*)(w + 64 * MB);
  u16* P   = (u16*)(w + 64 * MB);
  u16* R   = (u16*)(w + 96 * MB);
  float* Psup = (float*)w;
  float* Rsup = (float*)(w + 4 * MB);
  float* Msup = (float*)(w + 8 * MB);
  u16* attn = P;
  u16* Wsp = (u16*)(w + 128 * MB);
  const bool big = ws_size >= 144 * MB;

  const size_t DSZ = (size_t)B_ * S_ * D_;  // 16777216
  cvt_hi_kernel<<<2048, 256, 0, stream>>>(x, xh, (int)(DSZ / 4));

  dim3 gg(128, 8);
  if (big) {
    cvt_hi4_kernel<<<dim3(512, 4), 256, 0, stream>>>(Wq, Wk, Wv, Wo, Wsp, 262144);
    gemm_axw<1, float><<<gg, 256, 0, stream>>>(xh, Wsp + 0 * 1048576u, out, 16384, 1024, 1024);
    gemm_axw<1, u16><<<gg, 256, 0, stream>>>(xh, Wsp + 1 * 1048576u, Kbf, 16384, 1024, 1024);
    gemm_axw<1, u16><<<gg, 256, 0, stream>>>(xh, Wsp + 2 * 1048576u, Vbf, 16384, 1024, 1024);
    phase1_kernel<u16><<<dim3(NCHUNK, H_), 256, 0, stream>>>(out, Kbf, Vbf, P, R);
    seq_levelA<u16><<<dim3(NSUP, H_), 256, 0, stream>>>(P, R, Psup, Rsup);
    seq_levelB<<<dim3(H_), 256, 0, stream>>>(Psup, Rsup, Msup);
    seq_levelC<u16><<<dim3(NSUP, H_), 256, 0, stream>>>(P, R, Msup);
    phase3_kernel<u16><<<dim3(NCHUNK, H_), 256, 0, stream>>>(out, Vbf, R, attn);
    gemm_axw<1, float><<<gg, 256, 0, stream>>>(attn, Wsp + 3 * 1048576u, out, 16384, 1024, 1024);
  } else {
    gemm_axw<0, float><<<gg, 256, 0, stream>>>(xh, Wq, out, 16384, 1024, 1024);
    gemm_axw<0, u16><<<gg, 256, 0, stream>>>(xh, Wk, Kbf, 16384, 1024, 1024);
    gemm_axw<0, u16><<<gg, 256, 0, stream>>>(xh, Wv, Vbf, 16384, 1024, 1024);
    phase1_kernel<u16><<<dim3(NCHUNK, H_), 256, 0, stream>>>(out, Kbf, Vbf, P, R);
    seq_levelA<u16><<<dim3(NSUP, H_), 256, 0, stream>>>(P, R, Psup, Rsup);
    seq_levelB<<<dim3(H_), 256, 0, stream>>>(Psup, Rsup, Msup);
    seq_levelC<u16><<<dim3(NSUP, H_), 256, 0, stream>>>(P, R, Msup);
    phase3_kernel<u16><<<dim3(NCHUNK, H_), 256, 0, stream>>>(out, Vbf, R, attn);
    gemm_axw<0, float><<<gg, 256, 0, stream>>>(attn, Wo, out, 16384, 1024, 1024);
  }
}

// Round 16
// 524.832 us; speedup vs baseline: 1.1126x; 1.0256x over previous
//
#include <hip/hip_runtime.h>

// L2RegressionAttention — chunked WY-transform.
// r16: phase3 fused into levelC (attn = E*M0^T + F computed inline with the
// chunk-start Ms already in LDS; Mc global round-trip and phase3 launch
// eliminated; attn overwrites F in place, read-then-write same thread).
// GEMM/phase1/levelA/levelB byte-identical to r15.
// B=4, S=4096, D=1024, H=16, hd=64, eta = 0.1/4 = 0.025.

typedef unsigned short u16;
typedef __attribute__((ext_vector_type(8))) short short8;
typedef __attribute__((ext_vector_type(4))) float f32x4;

#define B_ 4
#define S_ 4096
#define D_ 1024
#define H_ 16
#define CHUNK 16
#define NCHUNK 256
#define SUPW 16
#define NSUP 16
#define ETA 0.025f

__device__ __forceinline__ u16 f2bf(float f) {
  unsigned u = __builtin_bit_cast(unsigned, f);
  u += 0x7fffu + ((u >> 16) & 1u);
  return (u16)(u >> 16);
}
__device__ __forceinline__ float bf2f(u16 s) {
  unsigned u = ((unsigned)s) << 16;
  return __builtin_bit_cast(float, u);
}
__device__ __forceinline__ float ldv(float v) { return v; }
__device__ __forceinline__ float ldv(u16 v) { return bf2f(v); }
__device__ __forceinline__ void stv(float* p, float v) { *p = v; }
__device__ __forceinline__ void stv(u16* p, float v) { *p = f2bf(v); }

#define MFMA __builtin_amdgcn_mfma_f32_16x16x32_bf16

__device__ __forceinline__ void gload16(const void* g, void* l) {
  __builtin_amdgcn_global_load_lds(
      (__attribute__((address_space(1))) void*)g,
      (__attribute__((address_space(3))) void*)l, 16, 0, 0);
}

// ---------------- fp32 -> bf16 hi-only convert ----------------
__global__ void cvt_hi_kernel(const float* __restrict__ x, u16* __restrict__ hi, int n4) {
  int i = blockIdx.x * blockDim.x + threadIdx.x;
  int stride = gridDim.x * blockDim.x;
  for (; i < n4; i += stride) {
    float4 v = ((const float4*)x)[i];
    ushort4 h;
    h.x = f2bf(v.x); h.y = f2bf(v.y); h.z = f2bf(v.z); h.w = f2bf(v.w);
    ((ushort4*)hi)[i] = h;
  }
}

__global__ void cvt_hi4_kernel(const float* __restrict__ a, const float* __restrict__ b,
                               const float* __restrict__ c, const float* __restrict__ d,
                               u16* __restrict__ o, int n4) {
  const float* src = (blockIdx.y == 0) ? a : (blockIdx.y == 1) ? b
                   : (blockIdx.y == 2) ? c : d;
  u16* dst = o + (size_t)blockIdx.y * 1048576u;
  int i = blockIdx.x * blockDim.x + threadIdx.x;
  int stride = gridDim.x * blockDim.x;
  for (; i < n4; i += stride) {
    float4 v = ((const float4*)src)[i];
    ushort4 h;
    h.x = f2bf(v.x); h.y = f2bf(v.y); h.z = f2bf(v.z); h.w = f2bf(v.w);
    ((ushort4*)dst)[i] = h;
  }
}

// ---------------- GEMM: C[M][N] = A * B^T (r12 optimum) ----------------
template<int BPRE, typename OutT>
__global__ __launch_bounds__(256) void gemm_axw(
    const u16* __restrict__ Ahg, const void* __restrict__ Bhp,
    OutT* __restrict__ C, int M, int N, int K) {
  __shared__ __align__(16) u16 Ahs[2][128][32];
  __shared__ __align__(16) u16 Bhs[2][128][32];
  const int tid = threadIdx.x, w = tid >> 6, lane = tid & 63;
  const int bm = blockIdx.x * 128, bn = blockIdx.y * 128;
  const int wm = (w >> 1) * 64, wn = (w & 1) * 64;
  const int fr = lane & 15, kb = lane >> 4;
  const int lrow = lane >> 2, lcol = (lane & 3) * 8;

  auto stage = [&](int buf, int k0) {
    {
      const size_t rb = (size_t)(bm + w * 32 + lrow) * K + k0 + lcol;
      gload16(Ahg + rb, &Ahs[buf][w * 32][0]);
      gload16(Ahg + rb + (size_t)16 * K, &Ahs[buf][w * 32 + 16][0]);
    }
    if constexpr (BPRE) {
      const u16* Bhg = (const u16*)Bhp;
      const size_t rb = (size_t)(bn + w * 32 + lrow) * K + k0 + lcol;
      gload16(Bhg + rb, &Bhs[buf][w * 32][0]);
      gload16(Bhg + rb + (size_t)16 * K, &Bhs[buf][w * 32 + 16][0]);
    } else {
      const float* Bm = (const float*)Bhp;
#pragma unroll
      for (int i2 = 0; i2 < 4; ++i2) {
        int e = tid + i2 * 256, r = e >> 3, sg = (e & 7) * 4;
        float4 v = *(const float4*)(&Bm[(size_t)(bn + r) * K + k0 + sg]);
        ushort4 hq;
        hq.x = f2bf(v.x); hq.y = f2bf(v.y); hq.z = f2bf(v.z); hq.w = f2bf(v.w);
        *(ushort4*)(&Bhs[buf][r][sg]) = hq;
      }
    }
  };
  auto compute = [&](int buf, f32x4 (*acc)[4]) {
    short8 ah[4], bh[4];
#pragma unroll
    for (int mi = 0; mi < 4; ++mi)
      ah[mi] = *(const short8*)(&Ahs[buf][wm + mi * 16 + fr][kb * 8]);
#pragma unroll
    for (int ni = 0; ni < 4; ++ni)
      bh[ni] = *(const short8*)(&Bhs[buf][wn + ni * 16 + fr][kb * 8]);
#pragma unroll
    for (int mi = 0; mi < 4; ++mi)
#pragma unroll
      for (int ni = 0; ni < 4; ++ni)
        acc[mi][ni] = MFMA(ah[mi], bh[ni], acc[mi][ni], 0, 0, 0);
  };

  f32x4 acc[4][4];
#pragma unroll
  for (int i = 0; i < 4; ++i)
#pragma unroll
    for (int j = 0; j < 4; ++j) acc[i][j] = (f32x4){0.f, 0.f, 0.f, 0.f};

  const int nt = K >> 5;
  stage(0, 0);
  asm volatile("s_waitcnt vmcnt(0)" ::: "memory");
  __syncthreads();
  int cur = 0;
  for (int t = 0; t < nt; ++t) {
    if (t + 1 < nt) stage(cur ^ 1, (t + 1) * 32);
    compute(cur, acc);
    asm volatile("s_waitcnt vmcnt(0)" ::: "memory");
    __syncthreads();
    cur ^= 1;
  }
  const int fc = lane & 15, fr4 = (lane >> 4) * 4;
#pragma unroll
  for (int mi = 0; mi < 4; ++mi)
#pragma unroll
    for (int ni = 0; ni < 4; ++ni) {
      int gm = bm + wm + mi * 16 + fr4;
      int gn = bn + wn + ni * 16 + fc;
#pragma unroll
      for (int rg = 0; rg < 4; ++rg)
        stv(&C[(size_t)(gm + rg) * N + gn], acc[mi][ni][rg]);
    }
}

// ---------------- phase 1 — unchanged r15 ----------------
template<typename PT>
__global__ __launch_bounds__(256) void phase1_kernel(
    float* __restrict__ Qg, const u16* __restrict__ Kg, u16* __restrict__ Vg,
    PT* __restrict__ Pg, PT* __restrict__ Rg) {
  __shared__ __align__(16) u16 Ks[64][72];
  __shared__ __align__(16) u16 KsT[64][72];
  __shared__ __align__(16) u16 Gh[64][72];
  __shared__ __align__(16) u16 Gl[64][72];
  __shared__ __align__(16) float Ut[64][68];
  __shared__ __align__(16) float Wt[64][68];

  const int c = blockIdx.x, h = blockIdx.y, tid = threadIdx.x;
  const int w = tid >> 6, lane = tid & 63;
  const int fr = lane & 15, kq = lane >> 4, orow = kq * 4;
  const int xr = 16 * w + fr;

  auto gidx = [&](int r, int d) -> size_t {
    return ((size_t)(r & 3) * S_ + (size_t)c * CHUNK + (r >> 2)) * D_ + h * 64 + d;
  };
  auto ldb = [&](const u16 (*M)[72], int row, int s) -> short8 {
    return *(const short8*)(&M[row][32 * s + 8 * kq]);
  };
  auto ldf = [&](const float (*M)[68], int row, int s, short8& hh, short8& ll) {
    const float* p = &M[row][32 * s + 8 * kq];
#pragma unroll
    for (int j = 0; j < 8; ++j) {
      float v = p[j];
      u16 hb = f2bf(v);
      hh[j] = (short)hb;
      ll[j] = (short)f2bf(v - bf2f(hb));
    }
  };
  auto ldfh = [&](const float (*M)[68], int row, int s) -> short8 {
    const float* p = &M[row][32 * s + 8 * kq];
    short8 hh;
#pragma unroll
    for (int j = 0; j < 8; ++j) hh[j] = (short)f2bf(p[j]);
    return hh;
  };

  for (int i = tid; i < 4096; i += 256) {
    int r = i >> 6, d = i & 63;
    size_t g = gidx(r, d);
    u16 kraw = Kg[g];
    Ks[r][d] = kraw;
    KsT[d][r] = kraw;
    Wt[d][r] = ETA * bf2f(kraw);
    Ut[d][r] = ETA * bf2f(Vg[g]);
  }
  __syncthreads();  // (1)

  f32x4 gacc[4];
#pragma unroll
  for (int ni = 0; ni < 4; ++ni) gacc[ni] = (f32x4){0.f, 0.f, 0.f, 0.f};
  {
    short8 xf[2];
#pragma unroll
    for (int s = 0; s < 2; ++s) xf[s] = ldb(Ks, xr, s);
#pragma unroll
    for (int ni = 0; ni < 4; ++ni)
#pragma unroll
      for (int s = 0; s < 2; ++s)
        gacc[ni] = MFMA(xf[s], ldb(Ks, 16 * ni + fr, s), gacc[ni], 0, 0, 0);
  }

  float sreg[4][4];
  {
    short8 xh[2], xl[2];
#pragma unroll
    for (int s = 0; s < 2; ++s) {
      const float* qp = &Qg[gidx(xr, 32 * s + 8 * kq)];
#pragma unroll
      for (int j = 0; j < 8; ++j) {
        float v = qp[j];
        u16 hb = f2bf(v);
        xh[s][j] = (short)hb;
        xl[s][j] = (short)f2bf(v - bf2f(hb));
      }
    }
    f32x4 acc[4];
#pragma unroll
    for (int ni = 0; ni < 4; ++ni) acc[ni] = (f32x4){0.f, 0.f, 0.f, 0.f};
#pragma unroll
    for (int ni = 0; ni < 4; ++ni)
#pragma unroll
      for (int s = 0; s < 2; ++s) {
        short8 yf = ldb(Ks, 16 * ni + fr, s);
        acc[ni] = MFMA(xh[s], yf, acc[ni], 0, 0, 0);
        acc[ni] = MFMA(xl[s], yf, acc[ni], 0, 0, 0);
      }
#pragma unroll
    for (int ni = 0; ni < 4; ++ni)
#pragma unroll
      for (int rg = 0; rg < 4; ++rg) {
        int r = 16 * w + orow + rg, cc = 16 * ni + fr;
        sreg[ni][rg] = ((r >> 2) >= (cc >> 2)) ? acc[ni][rg] : 0.f;
      }
  }
  __syncthreads();  // (1b)

#pragma unroll
  for (int ni = 0; ni < 4; ++ni)
#pragma unroll
    for (int rg = 0; rg < 4; ++rg) {
      float v = -ETA * gacc[ni][rg];
      u16 hb = f2bf(v);
      u16 lb = f2bf(v - bf2f(hb));
      int rr = 16 * w + orow + rg, cc = 16 * ni + fr;
      bool low = (rr >> 2) > (cc >> 2);
      u16 hm = low ? hb : (u16)0, lm = low ? lb : (u16)0;
      Gh[rr][cc] = hm;
      Gl[rr][cc] = lm;
      Ks[cc][rr] = hm;   // NU-h
    }
  __syncthreads();  // (2)

  {
    short8 uh[2], ul[2], wh[2], wl[2];
#pragma unroll
    for (int s = 0; s < 2; ++s) { ldf(Ut, xr, s, uh[s], ul[s]); ldf(Wt, xr, s, wh[s], wl[s]); }
    f32x4 aU[4], aW[4];
#pragma unroll
    for (int ni = 0; ni < 4; ++ni) { aU[ni] = (f32x4){0.f,0.f,0.f,0.f}; aW[ni] = (f32x4){0.f,0.f,0.f,0.f}; }
#pragma unroll
    for (int ni = 0; ni < 4; ++ni)
#pragma unroll
      for (int s = 0; s < 2; ++s) {
        short8 yh = ldb(Gh, 16 * ni + fr, s);
        short8 yl = ldb(Gl, 16 * ni + fr, s);
        aU[ni] = MFMA(uh[s], yh, aU[ni], 0, 0, 0);
        aU[ni] = MFMA(uh[s], yl, aU[ni], 0, 0, 0);
        aU[ni] = MFMA(ul[s], yh, aU[ni], 0, 0, 0);
        aW[ni] = MFMA(wh[s], yh, aW[ni], 0, 0, 0);
        aW[ni] = MFMA(wh[s], yl, aW[ni], 0, 0, 0);
        aW[ni] = MFMA(wl[s], yh, aW[ni], 0, 0, 0);
      }
#pragma unroll
    for (int ni = 0; ni < 4; ++ni)
#pragma unroll
      for (int rg = 0; rg < 4; ++rg) {
        Ut[16 * w + orow + rg][16 * ni + fr] += aU[ni][rg];
        Wt[16 * w + orow + rg][16 * ni + fr] += aW[ni][rg];
      }
  }
  auto appSf = [&](const u16 (*Np)[72]) {
    short8 xu[2], xw[2];
#pragma unroll
    for (int s = 0; s < 2; ++s) { xu[s] = ldfh(Ut, xr, s); xw[s] = ldfh(Wt, xr, s); }
    f32x4 aU[4], aW[4];
#pragma unroll
    for (int ni = 0; ni < 4; ++ni) { aU[ni] = (f32x4){0.f,0.f,0.f,0.f}; aW[ni] = (f32x4){0.f,0.f,0.f,0.f}; }
#pragma unroll
    for (int ni = 0; ni < 4; ++ni)
#pragma unroll
      for (int s = 0; s < 2; ++s) {
        short8 yf = ldb(Np, 16 * ni + fr, s);
        aU[ni] = MFMA(xu[s], yf, aU[ni], 0, 0, 0);
        aW[ni] = MFMA(xw[s], yf, aW[ni], 0, 0, 0);
      }
#pragma unroll
    for (int ni = 0; ni < 4; ++ni)
#pragma unroll
      for (int rg = 0; rg < 4; ++rg) {
        Ut[16 * w + orow + rg][16 * ni + fr] += aU[ni][rg];
        Wt[16 * w + orow + rg][16 * ni + fr] += aW[ni][rg];
      }
  };

  {
    f32x4 sq[4];
#pragma unroll
    for (int ni = 0; ni < 4; ++ni) sq[ni] = (f32x4){0.f, 0.f, 0.f, 0.f};
    short8 xh[2];
#pragma unroll
    for (int s = 0; s < 2; ++s) xh[s] = ldb(Gh, xr, s);
#pragma unroll
    for (int ni = 0; ni < 4; ++ni)
#pragma unroll
      for (int s = 0; s < 2; ++s)
        sq[ni] = MFMA(xh[s], ldb(Ks, 16 * ni + fr, s), sq[ni], 0, 0, 0);
    __syncthreads();  // (3)
#pragma unroll
    for (int ni = 0; ni < 4; ++ni)
#pragma unroll
      for (int rg = 0; rg < 4; ++rg) {
        u16 b = f2bf(sq[ni][rg]);
        int rr = 16 * w + orow + rg, cc = 16 * ni + fr;
        Ks[rr][cc] = b;
        Gh[cc][rr] = b;
      }
  }
  __syncthreads();  // (4)

  appSf(Ks);
  {
    f32x4 sq[4];
#pragma unroll
    for (int ni = 0; ni < 4; ++ni) sq[ni] = (f32x4){0.f, 0.f, 0.f, 0.f};
    short8 xf[2];
#pragma unroll
    for (int s = 0; s < 2; ++s) xf[s] = ldb(Ks, xr, s);
#pragma unroll
    for (int ni = 0; ni < 4; ++ni)
#pragma unroll
      for (int s = 0; s < 2; ++s)
        sq[ni] = MFMA(xf[s], ldb(Gh, 16 * ni + fr, s), sq[ni], 0, 0, 0);
    __syncthreads();  // (5)
#pragma unroll
    for (int ni = 0; ni < 4; ++ni)
#pragma unroll
      for (int rg = 0; rg < 4; ++rg) {
        u16 b = f2bf(sq[ni][rg]);
        int rr = 16 * w + orow + rg, cc = 16 * ni + fr;
        Gl[rr][cc] = b;
        Ks[cc][rr] = b;
      }
  }
  __syncthreads();  // (6)

  appSf(Gl);
  {
    f32x4 sq[4];
#pragma unroll
    for (int ni = 0; ni < 4; ++ni) sq[ni] = (f32x4){0.f, 0.f, 0.f, 0.f};
    short8 xf[2];
#pragma unroll
    for (int s = 0; s < 2; ++s) xf[s] = ldb(Gl, xr, s);
#pragma unroll
    for (int ni = 0; ni < 4; ++ni)
#pragma unroll
      for (int s = 0; s < 2; ++s)
        sq[ni] = MFMA(xf[s], ldb(Ks, 16 * ni + fr, s), sq[ni], 0, 0, 0);
#pragma unroll
    for (int ni = 0; ni < 4; ++ni)
#pragma unroll
      for (int rg = 0; rg < 4; ++rg)
        Gh[16 * w + orow + rg][16 * ni + fr] = f2bf(sq[ni][rg]);
  }
  __syncthreads();  // (7)

  appSf(Gh);
  __syncthreads();  // (7b)

  const size_t base = ((size_t)c * H_ + h) * 4096;
  {
    short8 wh[2], wl[2], uh[2], ul[2];
#pragma unroll
    for (int s = 0; s < 2; ++s) { ldf(Wt, xr, s, wh[s], wl[s]); ldf(Ut, xr, s, uh[s], ul[s]); }
    f32x4 aP[4], aR[4];
#pragma unroll
    for (int ni = 0; ni < 4; ++ni) { aP[ni] = (f32x4){0.f,0.f,0.f,0.f}; aR[ni] = (f32x4){0.f,0.f,0.f,0.f}; }
#pragma unroll
    for (int ni = 0; ni < 4; ++ni)
#pragma unroll
      for (int s = 0; s < 2; ++s) {
        short8 yf = ldb(KsT, 16 * ni + fr, s);
        aP[ni] = MFMA(wh[s], yf, aP[ni], 0, 0, 0);
        aP[ni] = MFMA(wl[s], yf, aP[ni], 0, 0, 0);
        aR[ni] = MFMA(uh[s], yf, aR[ni], 0, 0, 0);
        aR[ni] = MFMA(ul[s], yf, aR[ni], 0, 0, 0);
      }
#pragma unroll
    for (int ni = 0; ni < 4; ++ni)
#pragma unroll
      for (int rg = 0; rg < 4; ++rg) {
        stv(&Pg[base + (16 * w + orow + rg) * 64 + 16 * ni + fr], aP[ni][rg]);
        stv(&Rg[base + (16 * w + orow + rg) * 64 + 16 * ni + fr], aR[ni][rg]);
      }
  }
  {
    const int r = tid >> 2, d0 = (tid & 3) * 16;
    short8 v0, v1;
#pragma unroll
    for (int j = 0; j < 8; ++j) v0[j] = (short)f2bf(Wt[r][d0 + j]);
#pragma unroll
    for (int j = 0; j < 8; ++j) v1[j] = (short)f2bf(Wt[r][d0 + 8 + j]);
    *(short8*)(&Gh[r][d0]) = v0;
    *(short8*)(&Gh[r][d0 + 8]) = v1;
#pragma unroll
    for (int j = 0; j < 8; ++j) v0[j] = (short)f2bf(Ut[r][d0 + j]);
#pragma unroll
    for (int j = 0; j < 8; ++j) v1[j] = (short)f2bf(Ut[r][d0 + 8 + j]);
    *(short8*)(&Gl[r][d0]) = v0;
    *(short8*)(&Gl[r][d0 + 8]) = v1;
  }
#pragma unroll
  for (int ni = 0; ni < 4; ++ni)
#pragma unroll
    for (int rg = 0; rg < 4; ++rg)
      Ks[16 * w + orow + rg][16 * ni + fr] = f2bf(sreg[ni][rg]);
  __syncthreads();  // (8)

  {
    short8 xs[2];
#pragma unroll
    for (int s = 0; s < 2; ++s) xs[s] = ldb(Ks, xr, s);
    f32x4 accE[4], accF[4];
#pragma unroll
    for (int ni = 0; ni < 4; ++ni) {
      accE[ni] = (f32x4){0.f, 0.f, 0.f, 0.f};
      accF[ni] = (f32x4){0.f, 0.f, 0.f, 0.f};
    }
#pragma unroll
    for (int ni = 0; ni < 4; ++ni)
#pragma unroll
      for (int s = 0; s < 2; ++s) {
        accE[ni] = MFMA(xs[s], ldb(Gh, 16 * ni + fr, s), accE[ni], 0, 0, 0);
        accF[ni] = MFMA(xs[s], ldb(Gl, 16 * ni + fr, s), accF[ni], 0, 0, 0);
      }
#pragma unroll
    for (int ni = 0; ni < 4; ++ni)
#pragma unroll
      for (int rg = 0; rg < 4; ++rg) {
        int r = 16 * w + orow + rg, d = 16 * ni + fr;
        size_t g = gidx(r, d);
        float qv = Qg[g];
        Qg[g] = qv - accE[ni][rg];
        Vg[g] = f2bf(accF[ni][rg]);
      }
  }
}

// ---------------- scalar 64x64 helpers (levelB only) ----------------
__device__ __forceinline__ void store64(float* dst, const float (*src)[65], int tid) {
  for (int i = tid; i < 4096; i += 256) dst[i] = src[i >> 6][i & 63];
}
__device__ __forceinline__ void mm64(const float (*X)[65], const float (*Y)[65],
                                     float (*Dst)[65], const float (*Add)[65], int tid) {
  const int r0 = (tid >> 4) * 4, c0 = (tid & 15) * 4;
  float a[4][4] = {};
  for (int d = 0; d < 64; ++d) {
    float xv[4], yv[4];
#pragma unroll
    for (int i = 0; i < 4; ++i) xv[i] = X[r0 + i][d];
#pragma unroll
    for (int j = 0; j < 4; ++j) yv[j] = Y[d][c0 + j];
#pragma unroll
    for (int i = 0; i < 4; ++i)
#pragma unroll
      for (int j = 0; j < 4; ++j) a[i][j] += xv[i] * yv[j];
  }
  __syncthreads();
#pragma unroll
  for (int i = 0; i < 4; ++i)
#pragma unroll
    for (int j = 0; j < 4; ++j) {
      float v = a[i][j];
      if (Add) v += Add[r0 + i][c0 + j];
      Dst[r0 + i][c0 + j] = v;
    }
  __syncthreads();
}

// ---------------- level A (MFMA, bf16x3) — unchanged ----------------
template<typename PT>
__global__ __launch_bounds__(256) void seq_levelA(const PT* __restrict__ Pg,
    const PT* __restrict__ Rg, float* __restrict__ Psup, float* __restrict__ Rsup) {
  __shared__ __align__(16) float Pa[64][68], Ra[64][68], Ri[64][68];
  __shared__ __align__(16) u16 Pih[64][72], Pil[64][72];
  const int sup = blockIdx.x, h = blockIdx.y, tid = threadIdx.x;
  const int w = tid >> 6, lane = tid & 63;
  const int fr = lane & 15, kq = lane >> 4, orow = kq * 4;
  const int xr = 16 * w + fr;
  const int cbase = sup * SUPW;

  auto upd = [&](float (*St)[68], const float (*Add)[68]) {
    short8 xh[2], xl[2];
#pragma unroll
    for (int s2 = 0; s2 < 2; ++s2) {
      const float* p = &St[xr][32 * s2 + 8 * kq];
#pragma unroll
      for (int j = 0; j < 8; ++j) {
        float v = p[j];
        u16 hb = f2bf(v);
        xh[s2][j] = (short)hb;
        xl[s2][j] = (short)f2bf(v - bf2f(hb));
      }
    }
    f32x4 acc[4];
#pragma unroll
    for (int ni = 0; ni < 4; ++ni) acc[ni] = (f32x4){0.f, 0.f, 0.f, 0.f};
#pragma unroll
    for (int ni = 0; ni < 4; ++ni)
#pragma unroll
      for (int s2 = 0; s2 < 2; ++s2) {
        short8 yh = *(const short8*)(&Pih[16 * ni + fr][32 * s2 + 8 * kq]);
        short8 yl = *(const short8*)(&Pil[16 * ni + fr][32 * s2 + 8 * kq]);
        acc[ni] = MFMA(xh[s2], yh, acc[ni], 0, 0, 0);
        acc[ni] = MFMA(xh[s2], yl, acc[ni], 0, 0, 0);
        acc[ni] = MFMA(xl[s2], yh, acc[ni], 0, 0, 0);
      }
#pragma unroll
    for (int ni = 0; ni < 4; ++ni)
#pragma unroll
      for (int rg = 0; rg < 4; ++rg) {
        float v = acc[ni][rg];
        if (Add) v += Add[16 * w + orow + rg][16 * ni + fr];
        St[16 * w + orow + rg][16 * ni + fr] = v;
      }
  };

  {
    const PT* ps = Pg + ((size_t)cbase * H_ + h) * 4096;
    const PT* rs = Rg + ((size_t)cbase * H_ + h) * 4096;
    for (int i = tid; i < 4096; i += 256) {
      int r = i >> 6, cc = i & 63;
      Pa[r][cc] = ((r == cc) ? 1.f : 0.f) - ldv(ps[i]);
      Ra[r][cc] = ldv(rs[i]);
    }
  }
  float pf[16], rf[16];
  {
    const PT* ps = Pg + ((size_t)(cbase + 1) * H_ + h) * 4096;
    const PT* rs = Rg + ((size_t)(cbase + 1) * H_ + h) * 4096;
#pragma unroll
    for (int k = 0; k < 16; ++k) { int i = tid + k * 256; pf[k] = ldv(ps[i]); rf[k] = ldv(rs[i]); }
  }
  for (int s = 1; s < SUPW; ++s) {
#pragma unroll
    for (int k = 0; k < 16; ++k) {
      int i = tid + k * 256, d = i >> 6, cc = i & 63;
      float v = ((d == cc) ? 1.f : 0.f) - pf[k];
      u16 hb = f2bf(v);
      Pih[cc][d] = hb;
      Pil[cc][d] = f2bf(v - bf2f(hb));
      Ri[d][cc] = rf[k];
    }
    __syncthreads();
    if (s + 1 < SUPW) {
      const PT* ps = Pg + ((size_t)(cbase + s + 1) * H_ + h) * 4096;
      const PT* rs = Rg + ((size_t)(cbase + s + 1) * H_ + h) * 4096;
#pragma unroll
      for (int k = 0; k < 16; ++k) { int i = tid + k * 256; pf[k] = ldv(ps[i]); rf[k] = ldv(rs[i]); }
    }
    upd(Pa, nullptr);
    upd(Ra, Ri);
    __syncthreads();
  }
  for (int i = tid; i < 4096; i += 256) {
    Psup[((size_t)sup * H_ + h) * 4096 + i] = Pa[i >> 6][i & 63];
    Rsup[((size_t)sup * H_ + h) * 4096 + i] = Ra[i >> 6][i & 63];
  }
}

// ---------------- level B: exact fp32 scalar — unchanged ----------------
__global__ __launch_bounds__(256) void seq_levelB(const float* __restrict__ Psup,
    const float* __restrict__ Rsup, float* __restrict__ Msup) {
  __shared__ float Ms[64][65], Pi[64][65], Ri[64][65];
  const int h = blockIdx.x, tid = threadIdx.x;
  for (int i = tid; i < 4096; i += 256) Ms[i >> 6][i & 63] = 0.f;
  float pf[16], rf[16];
  {
    const float* ps = Psup + ((size_t)0 * H_ + h) * 4096;
    const float* rs = Rsup + ((size_t)0 * H_ + h) * 4096;
#pragma unroll
    for (int k = 0; k < 16; ++k) { int i = tid + k * 256; pf[k] = ps[i]; rf[k] = rs[i]; }
  }
  for (int s = 0; s < NSUP; ++s) {
#pragma unroll
    for (int k = 0; k < 16; ++k) {
      int i = tid + k * 256, r = i >> 6, cc = i & 63;
      Pi[r][cc] = pf[k];
      Ri[r][cc] = rf[k];
    }
    store64(Msup + ((size_t)s * H_ + h) * 4096, Ms, tid);
    __syncthreads();
    if (s + 1 < NSUP) {
      const float* ps = Psup + ((size_t)(s + 1) * H_ + h) * 4096;
      const float* rs = Rsup + ((size_t)(s + 1) * H_ + h) * 4096;
#pragma unroll
      for (int k = 0; k < 16; ++k) { int i = tid + k * 256; pf[k] = ps[i]; rf[k] = rs[i]; }
    }
    mm64(Ms, Pi, Ms, Ri, tid);
  }
}

// ---------------- level C fused with phase3 ----------------
// Per chunk s: attn_c = E_c * Ms^T + F_c (bf16x3 MFMA, Ms = M at chunk start,
// already in LDS), written over F in place; then Ms = Ms*Pi + Ri.
template<typename PT>
__global__ __launch_bounds__(256) void seq_levelC(const PT* __restrict__ Pg,
    const PT* __restrict__ Rg, const float* __restrict__ Msup,
    const float* __restrict__ Eg, u16* __restrict__ FAg) {
  __shared__ __align__(16) float Ms[64][68], Ri[64][68], Es[64][68];
  __shared__ __align__(16) u16 Pih[64][72], Pil[64][72];
  const int sup = blockIdx.x, h = blockIdx.y, tid = threadIdx.x;
  const int w = tid >> 6, lane = tid & 63;
  const int fr = lane & 15, kq = lane >> 4, orow = kq * 4;
  const int xr = 16 * w + fr;

  auto gidx = [&](int c, int r, int d) -> size_t {
    return ((size_t)(r & 3) * S_ + (size_t)c * CHUNK + (r >> 2)) * D_ + h * 64 + d;
  };
  auto ldf = [&](const float (*M)[68], int row, int s2, short8& hh, short8& ll) {
    const float* p = &M[row][32 * s2 + 8 * kq];
#pragma unroll
    for (int j = 0; j < 8; ++j) {
      float v = p[j];
      u16 hb = f2bf(v);
      hh[j] = (short)hb;
      ll[j] = (short)f2bf(v - bf2f(hb));
    }
  };

  auto upd = [&](float (*St)[68], const float (*Add)[68]) {
    short8 xh[2], xl[2];
#pragma unroll
    for (int s2 = 0; s2 < 2; ++s2) ldf(St, xr, s2, xh[s2], xl[s2]);
    f32x4 acc[4];
#pragma unroll
    for (int ni = 0; ni < 4; ++ni) acc[ni] = (f32x4){0.f, 0.f, 0.f, 0.f};
#pragma unroll
    for (int ni = 0; ni < 4; ++ni)
#pragma unroll
      for (int s2 = 0; s2 < 2; ++s2) {
        short8 yh = *(const short8*)(&Pih[16 * ni + fr][32 * s2 + 8 * kq]);
        short8 yl = *(const short8*)(&Pil[16 * ni + fr][32 * s2 + 8 * kq]);
        acc[ni] = MFMA(xh[s2], yh, acc[ni], 0, 0, 0);
        acc[ni] = MFMA(xh[s2], yl, acc[ni], 0, 0, 0);
        acc[ni] = MFMA(xl[s2], yh, acc[ni], 0, 0, 0);
      }
#pragma unroll
    for (int ni = 0; ni < 4; ++ni)
#pragma unroll
      for (int rg = 0; rg < 4; ++rg) {
        float v = acc[ni][rg];
        if (Add) v += Add[16 * w + orow + rg][16 * ni + fr];
        St[16 * w + orow + rg][16 * ni + fr] = v;
      }
  };

  for (int i = tid; i < 4096; i += 256)
    Ms[i >> 6][i & 63] = Msup[((size_t)sup * H_ + h) * 4096 + i];
  float pf[16], rf[16], ef[16];
  {
    const size_t slice = ((size_t)(sup * SUPW) * H_ + h) * 4096;
    const int c0 = sup * SUPW;
#pragma unroll
    for (int k = 0; k < 16; ++k) {
      int i = tid + k * 256;
      pf[k] = ldv(Pg[slice + i]);
      rf[k] = ldv(Rg[slice + i]);
      ef[k] = Eg[gidx(c0, i >> 6, i & 63)];
    }
  }
  for (int s = 0; s < SUPW; ++s) {
    const int c = sup * SUPW + s;
#pragma unroll
    for (int k = 0; k < 16; ++k) {
      int i = tid + k * 256, d = i >> 6, cc = i & 63;
      float v = ((d == cc) ? 1.f : 0.f) - pf[k];
      u16 hb = f2bf(v);
      Pih[cc][d] = hb;
      Pil[cc][d] = f2bf(v - bf2f(hb));
      Ri[d][cc] = rf[k];
      Es[d][cc] = ef[k];
    }
    __syncthreads();  // staged
    if (s + 1 < SUPW) {
      const size_t sl2 = ((size_t)(c + 1) * H_ + h) * 4096;
#pragma unroll
      for (int k = 0; k < 16; ++k) {
        int i = tid + k * 256;
        pf[k] = ldv(Pg[sl2 + i]);
        rf[k] = ldv(Rg[sl2 + i]);
        ef[k] = Eg[gidx(c + 1, i >> 6, i & 63)];
      }
    }
    // attn = E * Ms^T + F  (bf16x3; Ms stable until upd after the barrier)
    {
      short8 exh[2], exl[2];
#pragma unroll
      for (int s2 = 0; s2 < 2; ++s2) ldf(Es, xr, s2, exh[s2], exl[s2]);
      f32x4 at[4];
#pragma unroll
      for (int ni = 0; ni < 4; ++ni) at[ni] = (f32x4){0.f, 0.f, 0.f, 0.f};
#pragma unroll
      for (int ni = 0; ni < 4; ++ni)
#pragma unroll
        for (int s2 = 0; s2 < 2; ++s2) {
          short8 yh, yl;
          ldf(Ms, 16 * ni + fr, s2, yh, yl);
          at[ni] = MFMA(exh[s2], yh, at[ni], 0, 0, 0);
          at[ni] = MFMA(exh[s2], yl, at[ni], 0, 0, 0);
          at[ni] = MFMA(exl[s2], yh, at[ni], 0, 0, 0);
        }
#pragma unroll
      for (int ni = 0; ni < 4; ++ni)
#pragma unroll
        for (int rg = 0; rg < 4; ++rg) {
          int r = 16 * w + orow + rg, d = 16 * ni + fr;
          size_t g = gidx(c, r, d);
          FAg[g] = f2bf(at[ni][rg] + bf2f(FAg[g]));  // read F, write attn (same thread)
        }
    }
    __syncthreads();  // all Ms reads done before upd writes
    upd(Ms, Ri);
    __syncthreads();
  }
}

// ---------------- launch ----------------
extern "C" void kernel_launch(void* const* d_in, const int* in_sizes, int n_in,
                              void* d_out, int out_size, void* d_ws, size_t ws_size,
                              hipStream_t stream) {
  (void)in_sizes; (void)n_in; (void)out_size;
  const float* x  = (const float*)d_in[0];
  const float* Wq = (const float*)d_in[1];
  const float* Wk = (const float*)d_in[2];
  const float* Wv = (const float*)d_in[3];
  const float* Wo = (const float*)d_in[4];
  float* out = (float*)d_out;

  char* w = (char*)d_ws;
  const size_t MB = 1024 * 1024;
  // [0,32) Kbf -> smalls ; [32,64) Vbf: V -> F -> attn ; [64,96) xh -> P bf16 ;
  // [96,128) R bf16 ; [128,136) Wsp (4x 1M u16: q,k,v,o)
  u16* Kbf = (u16*)w;
  u16* Vbf = (u16*)(w + 32 * MB);
  u16* xh  = (u16*)(w + 64 * MB);
  u16* P   = (u16*)(w + 64 * MB);
  u16* R   = (u16*)(w + 96 * MB);
  float* Psup = (float*)w;
  float* Rsup = (float*)(w + 4 * MB);
  float* Msup = (float*)(w + 8 * MB);
  u16* Wsp = (u16*)(w + 128 * MB);
  const bool big = ws_size >= 144 * MB;

  const size_t DSZ = (size_t)B_ * S_ * D_;  // 16777216
  cvt_hi_kernel<<<2048, 256, 0, stream>>>(x, xh, (int)(DSZ / 4));

  dim3 gg(128, 8);
  if (big) {
    cvt_hi4_kernel<<<dim3(512, 4), 256, 0, stream>>>(Wq, Wk, Wv, Wo, Wsp, 262144);
    gemm_axw<1, float><<<gg, 256, 0, stream>>>(xh, Wsp + 0 * 1048576u, out, 16384, 1024, 1024);
    gemm_axw<1, u16><<<gg, 256, 0, stream>>>(xh, Wsp + 1 * 1048576u, Kbf, 16384, 1024, 1024);
    gemm_axw<1, u16><<<gg, 256, 0, stream>>>(xh, Wsp + 2 * 1048576u, Vbf, 16384, 1024, 1024);
    phase1_kernel<u16><<<dim3(NCHUNK, H_), 256, 0, stream>>>(out, Kbf, Vbf, P, R);
    seq_levelA<u16><<<dim3(NSUP, H_), 256, 0, stream>>>(P, R, Psup, Rsup);
    seq_levelB<<<dim3(H_), 256, 0, stream>>>(Psup, Rsup, Msup);
    seq_levelC<u16><<<dim3(NSUP, H_), 256, 0, stream>>>(P, R, Msup, out, Vbf);
    gemm_axw<1, float><<<gg, 256, 0, stream>>>(Vbf, Wsp + 3 * 1048576u, out, 16384, 1024, 1024);
  } else {
    gemm_axw<0, float><<<gg, 256, 0, stream>>>(xh, Wq, out, 16384, 1024, 1024);
    gemm_axw<0, u16><<<gg, 256, 0, stream>>>(xh, Wk, Kbf, 16384, 1024, 1024);
    gemm_axw<0, u16><<<gg, 256, 0, stream>>>(xh, Wv, Vbf, 16384, 1024, 1024);
    phase1_kernel<u16><<<dim3(NCHUNK, H_), 256, 0, stream>>>(out, Kbf, Vbf, P, R);
    seq_levelA<u16><<<dim3(NSUP, H_), 256, 0, stream>>>(P, R, Psup, Rsup);
    seq_levelB<<<dim3(H_), 256, 0, stream>>>(Psup, Rsup, Msup);
    seq_levelC<u16><<<dim3(NSUP, H_), 256, 0, stream>>>(P, R, Msup, out, Vbf);
    gemm_axw<0, float><<<gg, 256, 0, stream>>>(Vbf, Wo, out, 16384, 1024, 1024);
  }
}